// Round 10
// baseline (116646.838 us; speedup 1.0000x reference)
//
#include <hip/hip_runtime.h>
#include <stdint.h>

#define HH 640
#define BB 128
#define TT 512
#define VV 4097
#define G4 2560
#define VP3 4352     // padded Wout cols (34*128; tiles 0..32 real, 33 zero)
#define XSZ 81920    // 640*128 state floats

__device__ __forceinline__ float sigm(float x){ return 1.0f/(1.0f+expf(-x)); }

__device__ __forceinline__ unsigned long long packkey(float f, unsigned v){
    unsigned u = __float_as_uint(f);
    unsigned m = (u & 0x80000000u) ? ~u : (u | 0x80000000u);
    return ((unsigned long long)m << 32) | (unsigned long long)(~v);
}
__device__ __forceinline__ float vld(const float* p){ return *(const volatile float*)p; }
__device__ __forceinline__ void  vst(float* p, float v){ *(volatile float*)p = v; }
__device__ __forceinline__ int   vldi(const int* p){ return *(const volatile int*)p; }
__device__ __forceinline__ void  vsti(int* p, int v){ *(volatile int*)p = v; }
__device__ __forceinline__ unsigned long long ald8(const void* p){
    return __hip_atomic_load((const unsigned long long*)p, __ATOMIC_RELAXED, __HIP_MEMORY_SCOPE_AGENT);
}
__device__ __forceinline__ void ast8(void* p, unsigned long long v){
    __hip_atomic_store((unsigned long long*)p, v, __ATOMIC_RELAXED, __HIP_MEMORY_SCOPE_AGENT);
}
__device__ __forceinline__ float aldf(const float* p){
    unsigned u = __hip_atomic_load((const unsigned*)p, __ATOMIC_RELAXED, __HIP_MEMORY_SCOPE_AGENT);
    return __uint_as_float(u);
}
__device__ __forceinline__ void astf(float* p, float v){
    __hip_atomic_store((unsigned*)p, __float_as_uint(v), __ATOMIC_RELAXED, __HIP_MEMORY_SCOPE_AGENT);
}
// sc1 float4 load (16B-aligned) from LLC-domain data
__device__ __forceinline__ float4 vld4(const float* p){
    unsigned long long a = ald8(p), b = ald8(p+2);
    float4 r;
    r.x = __uint_as_float((unsigned)a); r.y = __uint_as_float((unsigned)(a>>32));
    r.z = __uint_as_float((unsigned)b); r.w = __uint_as_float((unsigned)(b>>32));
    return r;
}

// ---------------- init ----------------
__global__ __launch_bounds__(256) void k_init7(const float* __restrict__ h0, const float* __restrict__ c0,
                       float* __restrict__ hA, float* __restrict__ cA, float* __restrict__ hS,
                       int* __restrict__ labelp, unsigned long long* __restrict__ slotX,
                       int* __restrict__ ctrl){
    int i = blockIdx.x*256 + threadIdx.x;
    if (i < BB*HH){
        int b = i / HH, jj = i % HH;
        size_t o = (size_t)jj*128 + b;
        hA[o] = h0[i]; cA[o] = c0[i]; hS[o] = h0[i];
    }
    if (i < 1024) labelp[i] = 0;
    if (i < 2048) slotX[i] = 0ULL;
    if (i < 8192) ctrl[i] = 0;
}

// ---------------- transposes (R5/R7-proven) ----------------
__global__ __launch_bounds__(256) void k_tr_gate(const float* __restrict__ W, float* __restrict__ WT){
    int idx = blockIdx.x*256 + threadIdx.x;
    if (idx >= G4*160) return;
    int row = idx / 160, kq = idx % 160;
    int g = row / HH, jj = row % HH;
    float4 f = *reinterpret_cast<const float4*>(W + (size_t)row*HH + kq*4);
    WT[(size_t)(kq*4+0)*G4 + jj*4+g] = f.x;
    WT[(size_t)(kq*4+1)*G4 + jj*4+g] = f.y;
    WT[(size_t)(kq*4+2)*G4 + jj*4+g] = f.z;
    WT[(size_t)(kq*4+3)*G4 + jj*4+g] = f.w;
}
__global__ __launch_bounds__(256) void k_tr640(const float* __restrict__ W, float* __restrict__ WT){
    int idx = blockIdx.x*256 + threadIdx.x;
    if (idx >= HH*160) return;
    int n = idx / 160, kq = idx % 160;
    float4 f = *reinterpret_cast<const float4*>(W + (size_t)n*HH + kq*4);
    WT[(size_t)(kq*4+0)*HH + n] = f.x;
    WT[(size_t)(kq*4+1)*HH + n] = f.y;
    WT[(size_t)(kq*4+2)*HH + n] = f.z;
    WT[(size_t)(kq*4+3)*HH + n] = f.w;
}
__global__ __launch_bounds__(256) void k_tr_woutr(const float* __restrict__ W, float* __restrict__ WT){
    int idx = blockIdx.x*256 + threadIdx.x;
    if (idx >= VP3*160) return;
    int v = idx / 160, kq = idx % 160;
    float4 f = make_float4(0.f,0.f,0.f,0.f);
    if (v < VV) f = *reinterpret_cast<const float4*>(W + (size_t)v*HH + kq*4);
    WT[(size_t)(kq*4+0)*VP3 + v] = f.x;
    WT[(size_t)(kq*4+1)*VP3 + v] = f.y;
    WT[(size_t)(kq*4+2)*VP3 + v] = f.z;
    WT[(size_t)(kq*4+3)*VP3 + v] = f.w;
}
__global__ __launch_bounds__(256) void k_boutp(const float* __restrict__ b_out, float* __restrict__ bp){
    int v = blockIdx.x*256 + threadIdx.x;
    if (v < VP3) bp[v] = (v < VV) ? b_out[v] : -1e30f;
}

// ---------------- emb_proj (R4-proven, direct emb reads) ----------------
typedef float f32x4v __attribute__((ext_vector_type(4)));
__global__ __launch_bounds__(256) void k_embproj2(const float* __restrict__ emb,
                          const float* __restrict__ WihT,
                          const float* __restrict__ b_ih, const float* __restrict__ b_hh,
                          float* __restrict__ embproj){
    __shared__ float lw[640*16];
    int vt = blockIdx.x / 160, ut = blockIdx.x % 160;
    for (int i=threadIdx.x; i<640*16; i+=256)
        lw[i] = WihT[(size_t)(i>>4)*G4 + ut*16 + (i&15)];
    float bias[16];
    #pragma unroll
    for (int u=0;u<16;++u){
        int gu = ut*16+u, jj = gu>>2, g = gu&3;
        bias[u] = b_ih[g*HH+jj] + b_hh[g*HH+jj];
    }
    __syncthreads();
    int v = vt*256 + threadIdx.x;
    float acc[16];
    #pragma unroll
    for (int u=0;u<16;++u) acc[u]=0.f;
    if (v < VV){
        const float4* er = reinterpret_cast<const float4*>(emb + (size_t)v*HH);
        for (int k4=0;k4<160;++k4){
            float4 ev = er[k4];
            #pragma unroll
            for (int q=0;q<4;++q){
                float e = (q==0)?ev.x:(q==1)?ev.y:(q==2)?ev.z:ev.w;
                const f32x4v* wr = reinterpret_cast<const f32x4v*>(&lw[(k4*4+q)*16]);
                #pragma unroll
                for (int g=0; g<4; ++g){
                    f32x4v w = wr[g];
                    #pragma unroll
                    for (int ee=0; ee<4; ++ee) acc[g*4+ee] = fmaf(w[ee], e, acc[g*4+ee]);
                }
            }
        }
    }
    if (v <= VV){
        #pragma unroll
        for (int q=0;q<4;++q){
            float4 st = make_float4(acc[q*4+0]+bias[q*4+0], acc[q*4+1]+bias[q*4+1],
                                    acc[q*4+2]+bias[q*4+2], acc[q*4+3]+bias[q*4+3]);
            *reinterpret_cast<float4*>(embproj + (size_t)v*G4 + ut*16 + q*4) = st;
        }
    }
}

// ---------------- enc_proj precompute, layout [t][n][b] ----------------
__global__ __launch_bounds__(128) void k_encprojT2(const float* __restrict__ x,
                          const float* __restrict__ WencT, const float* __restrict__ b_enc,
                          float* __restrict__ encprojT){
    int tile = (blockIdx.x & 7)*2560 + (blockIdx.x >> 3);
    int b   = tile / 160;
    int rem = tile % 160;
    int tt  = rem / 5;
    int nt2 = rem % 5;
    int n = nt2*128 + threadIdx.x;
    float acc[16];
    #pragma unroll
    for (int i=0;i<16;i++) acc[i]=0.f;
    const float* xb = x + (size_t)b*HH*TT + tt*16;
    #pragma unroll 4
    for (int k=0;k<HH;++k){
        float wv = WencT[(size_t)k*HH + n];
        const float4* xp = reinterpret_cast<const float4*>(xb + (size_t)k*TT);
        float4 x0=xp[0], x1=xp[1], x2=xp[2], x3=xp[3];
        acc[0]=fmaf(x0.x,wv,acc[0]);  acc[1]=fmaf(x0.y,wv,acc[1]);
        acc[2]=fmaf(x0.z,wv,acc[2]);  acc[3]=fmaf(x0.w,wv,acc[3]);
        acc[4]=fmaf(x1.x,wv,acc[4]);  acc[5]=fmaf(x1.y,wv,acc[5]);
        acc[6]=fmaf(x1.z,wv,acc[6]);  acc[7]=fmaf(x1.w,wv,acc[7]);
        acc[8]=fmaf(x2.x,wv,acc[8]);  acc[9]=fmaf(x2.y,wv,acc[9]);
        acc[10]=fmaf(x2.z,wv,acc[10]); acc[11]=fmaf(x2.w,wv,acc[11]);
        acc[12]=fmaf(x3.x,wv,acc[12]); acc[13]=fmaf(x3.y,wv,acc[13]);
        acc[14]=fmaf(x3.z,wv,acc[14]); acc[15]=fmaf(x3.w,wv,acc[15]);
    }
    float be = b_enc[n];
    #pragma unroll
    for (int ti=0; ti<16; ++ti)
        encprojT[((size_t)(tt*16+ti)*HH + n)*BB + b] = acc[ti] + be;
}

// ---------------- gA init: gates(0) = Whh @ h0 ----------------
__global__ __launch_bounds__(256) void k_gA02(const float* __restrict__ WhhT,
                       const float* __restrict__ hS, float* __restrict__ gA){
    int idx = blockIdx.x*256 + threadIdx.x;   // G4*BB = 327680
    if (idx >= G4*BB) return;
    int u = idx >> 7, b = idx & 127;
    float a = 0.f;
    #pragma unroll 4
    for (int k=0;k<HH;++k)
        a = fmaf(WhhT[(size_t)k*G4 + u], hS[(size_t)k*128 + b], a);
    gA[((size_t)(u>>2)*128 + b)*4 + (u&3)] = a;
}

// ---------------- flag barrier (no RMW) ----------------
__device__ __forceinline__ void xbar(int* arrL, int* lrelL, int* xdG, int* grG,
                                     int x, int r, int R, unsigned ph, bool glob){
    asm volatile("s_waitcnt vmcnt(0) lgkmcnt(0)" ::: "memory");
    __syncthreads();
    if (threadIdx.x == 0){
        vsti(&arrL[r*16], (int)ph);
        if (r == 0){
            long spin = 0;
            for(;;){
                bool ok = true;
                for (int q=1; q<R; ++q) if ((unsigned)vldi(&arrL[q*16]) < ph){ ok=false; break; }
                if (ok) break;
                if (++spin > 200000000L) break;
            }
            if (glob){
                __hip_atomic_store(&xdG[x*16], (int)ph, __ATOMIC_RELAXED, __HIP_MEMORY_SCOPE_AGENT);
                if (x == 0){
                    spin = 0;
                    for(;;){
                        bool ok = true;
                        for (int q=0; q<8; ++q)
                            if ((unsigned)__hip_atomic_load(&xdG[q*16], __ATOMIC_RELAXED, __HIP_MEMORY_SCOPE_AGENT) < ph){ ok=false; break; }
                        if (ok) break;
                        if (++spin > 200000000L) break;
                    }
                    for (int q=0; q<8; ++q)
                        __hip_atomic_store(&grG[q*16], (int)ph, __ATOMIC_RELAXED, __HIP_MEMORY_SCOPE_AGENT);
                } else {
                    spin = 0;
                    while ((unsigned)__hip_atomic_load(&grG[x*16], __ATOMIC_RELAXED, __HIP_MEMORY_SCOPE_AGENT) < ph
                           && spin < 200000000L) ++spin;
                }
            }
            vsti(&lrelL[0], (int)ph);
        } else {
            long spin = 0;
            while ((unsigned)vldi(&lrelL[0]) < ph && spin < 400000000L) ++spin;
        }
    }
    __syncthreads();
    asm volatile("" ::: "memory");
}

// ================= persistent kernel =================
__global__ __launch_bounds__(512,1) void k_run4(
    const float* __restrict__ WhhT, const float* __restrict__ WpredT,
    const float* __restrict__ WoutTr,
    const float* __restrict__ b_pred, const float* __restrict__ boutP,
    const float* __restrict__ embproj, const float* __restrict__ encprojT,
    const int* __restrict__ lens,
    float* gA, float* gB, float* cA, float* cB, float* hA,
    float* hS, float* jlp,
    unsigned long long* slotX, int* labelp,
    int* ctrl, float* dout)
{
    __shared__ float stage[20480];              // 80 KB
    __shared__ float red[6144];                 // 24 KB
    __shared__ unsigned long long keysM[512];   //  4 KB
    __shared__ int sSel[128];
    __shared__ unsigned char sMask[128];
    __shared__ int s_r, s_R;
    float4* st4 = reinterpret_cast<float4*>(stage);
    const int tid = threadIdx.x;
    int x = __builtin_amdgcn_s_getreg(63508) & 7;

    if (tid == 0){
        s_r = (int)__hip_atomic_fetch_add((unsigned*)&ctrl[x], 1u, __ATOMIC_RELAXED, __HIP_MEMORY_SCOPE_AGENT);
        __hip_atomic_fetch_add((unsigned*)&ctrl[16], 1u, __ATOMIC_RELAXED, __HIP_MEMORY_SCOPE_AGENT);
        long spin = 0;
        while (__hip_atomic_load((unsigned*)&ctrl[16], __ATOMIC_RELAXED, __HIP_MEMORY_SCOPE_AGENT) < 256u
               && spin < 400000000L){ __builtin_amdgcn_s_sleep(1); ++spin; }
        s_R = (int)__hip_atomic_load((unsigned*)&ctrl[x], __ATOMIC_RELAXED, __HIP_MEMORY_SCOPE_AGENT);
    }
    __syncthreads();
    const int r = s_r, R = s_R;

    int* arrL  = ctrl + 64 + x*512;
    int* lrelL = ctrl + 4800 + x*16;
    int* xdG   = ctrl + 5120;
    int* grG   = ctrl + 5376;

    float* jl = jlp + (size_t)x*XSZ;
    int* lab  = labelp + x*128;

    // gate tile ownership (20 tiles of 128 u = 32 jj)
    int gt[3]; int ngt;
    if (x < 4){ gt[0]=2*x; gt[1]=2*x+1; gt[2]=16+x; ngt=3; }
    else      { gt[0]=2*x; gt[1]=2*x+1; gt[2]=0;    ngt=2; }
    const int njj = ngt*32;
    // P2 tile list: 5 joint + owned gates
    int tl[8]; int nt2 = 5+ngt;
    tl[0]=20; tl[1]=21; tl[2]=22; tl[3]=23; tl[4]=24;
    for (int q=0;q<ngt;++q) tl[5+q]=gt[q];
    const int NJ2 = nt2*4;
    const int nt3 = (x==7)?5:4;
    const int NJ3 = nt3*8;

    unsigned ph = 0;
    for (int t = 0; t < TT; ++t){
        const int pr = (t-1)&1, pw = t&1;
        unsigned long long* slotR = slotX + (size_t)pr*1024;
        unsigned long long* slotW = slotX + (size_t)pw*1024;

        // ---- P1 prep (per-b decision, redundant per block) ----
        if (tid < 128){
            int b = tid;
            bool mask; int sel=0, kprev=0;
            if (t == 0){ mask = true; sel = 0; }
            else {
                unsigned long long m = 0ULL;
                #pragma unroll
                for (int y=0;y<8;++y){
                    unsigned long long v = ald8(&slotR[y*128+b]);
                    if (v > m) m = v;
                }
                int k = (m==0ULL) ? 0 : (int)(~(unsigned)m);
                int lb = vldi(&lab[b]);
                mask = ((t-1) >= lens[b]) || (k == 0);
                kprev = k; sel = mask ? lb : k;
            }
            sMask[b] = mask ? 1 : 0; sSel[b] = (t==0) ? VV : sel;
            if (r == 0){
                vsti(&lab[b], sel);                 // idempotent-select race-safe
                ast8(&slotW[x*128+b], 0ULL);
                if (x == 0 && t > 0) dout[(size_t)b*TT + (t-1)] = mask ? 0.f : (float)kprev;
            }
        }
        __syncthreads();

        // ---- P1: select + LSTM nonlin on owned jj-slice ----
        for (int idx = r*512 + tid; idx < njj*128; idx += R*512){
            int jjl = idx >> 7, b = idx & 127;
            int jj = gt[jjl>>5]*32 + (jjl & 31);
            bool mask = sMask[b] != 0;
            size_t o = (size_t)jj*128 + b;
            size_t o4 = o*4;
            float g0,g1,g2,g3;
            if (mask){
                g0 = vld(gA+o4+0); g1 = vld(gA+o4+1); g2 = vld(gA+o4+2); g3 = vld(gA+o4+3);
            } else {
                g0 = vld(gB+o4+0); g1 = vld(gB+o4+1); g2 = vld(gB+o4+2); g3 = vld(gB+o4+3);
                vst(gA+o4+0,g0); vst(gA+o4+1,g1); vst(gA+o4+2,g2); vst(gA+o4+3,g3);
            }
            float4 e = *reinterpret_cast<const float4*>(embproj + (size_t)sSel[b]*G4 + jj*4);
            float gi = g0+e.x, gf = g1+e.y, gg = g2+e.z, go = g3+e.w;
            float ce = mask ? vld(cA+o) : vld(cB+o);
            float cv = sigm(gf)*ce + sigm(gi)*tanhf(gg);
            float h2 = sigm(go)*tanhf(cv);
            float hprev = mask ? vld(hA+o) : aldf(&hS[o]);
            vst(cA+o, ce); vst(cB+o, cv); vst(hA+o, hprev);
            astf(&hS[o], h2);
        }
        ++ph; xbar(arrL, lrelL, xdG, grG, x, r, R, ph, true);   // GLOBAL: h1 ready

        // ---- P2: joint (redundant) + owned gate tiles; job = (tile, 32b) ----
        for (int j = r; j < NJ2; j += R){
            int tile = tl[j>>2]; int bq = j & 3;
            __syncthreads();
            for (int i = tid; i < 5120; i += 512){
                int k = i >> 3, q = i & 7;
                st4[i] = vld4(&hS[(size_t)k*128 + bq*32 + q*4]);
            }
            __syncthreads();
            const int cg = tid & 31, bg = (tid>>5) & 7, kq = tid >> 8;
            const float* Wb; int ldc, c0;
            if (tile >= 20){ Wb = WpredT; ldc = HH;  c0 = (tile-20)*128 + cg*4; }
            else           { Wb = WhhT;  ldc = G4;  c0 = tile*128 + cg*4; }
            float acc[4][4];
            #pragma unroll
            for (int i2=0;i2<4;++i2)
                #pragma unroll
                for (int j2=0;j2<4;++j2) acc[i2][j2]=0.f;
            #pragma unroll 4
            for (int k = kq*320; k < kq*320+320; ++k){
                float4 w4 = *reinterpret_cast<const float4*>(&Wb[(size_t)k*ldc + c0]);
                float4 h4 = st4[k*8 + bg];
                acc[0][0]=fmaf(w4.x,h4.x,acc[0][0]); acc[0][1]=fmaf(w4.x,h4.y,acc[0][1]);
                acc[0][2]=fmaf(w4.x,h4.z,acc[0][2]); acc[0][3]=fmaf(w4.x,h4.w,acc[0][3]);
                acc[1][0]=fmaf(w4.y,h4.x,acc[1][0]); acc[1][1]=fmaf(w4.y,h4.y,acc[1][1]);
                acc[1][2]=fmaf(w4.y,h4.z,acc[1][2]); acc[1][3]=fmaf(w4.y,h4.w,acc[1][3]);
                acc[2][0]=fmaf(w4.z,h4.x,acc[2][0]); acc[2][1]=fmaf(w4.z,h4.y,acc[2][1]);
                acc[2][2]=fmaf(w4.z,h4.z,acc[2][2]); acc[2][3]=fmaf(w4.z,h4.w,acc[2][3]);
                acc[3][0]=fmaf(w4.w,h4.x,acc[3][0]); acc[3][1]=fmaf(w4.w,h4.y,acc[3][1]);
                acc[3][2]=fmaf(w4.w,h4.z,acc[3][2]); acc[3][3]=fmaf(w4.w,h4.w,acc[3][3]);
            }
            int slot = tid & 255;
            if (kq == 1){
                #pragma unroll
                for (int i2=0;i2<4;++i2)
                    #pragma unroll
                    for (int j2=0;j2<4;++j2) red[slot*16 + i2*4+j2] = acc[i2][j2];
            }
            __syncthreads();
            if (kq == 0){
                int b0 = bq*32 + bg*4;
                #pragma unroll
                for (int i2=0;i2<4;++i2){
                    int c = c0 + i2;
                    if (tile >= 20){
                        float bp = b_pred[c];
                        #pragma unroll
                        for (int j2=0;j2<4;++j2){
                            float sv = acc[i2][j2] + red[slot*16 + i2*4+j2] + bp
                                     + encprojT[((size_t)t*HH + c)*BB + b0+j2];
                            vst(&jl[(size_t)c*128 + b0+j2], fmaxf(sv, 0.f));
                        }
                    } else {
                        int jj = c >> 2, g = c & 3;
                        #pragma unroll
                        for (int j2=0;j2<4;++j2){
                            float sv = acc[i2][j2] + red[slot*16 + i2*4+j2];
                            vst(&gB[((size_t)jj*128 + b0+j2)*4 + g], sv);
                        }
                    }
                }
            }
        }
        ++ph; xbar(arrL, lrelL, xdG, grG, x, r, R, ph, false);  // LOCAL: joint ready

        // ---- P3: owned vocab tiles + argmax; job = (tile, 16b) ----
        for (int j = r; j < NJ3; j += R){
            int ti = j >> 3, bh = j & 7;
            int tile = (ti < 4) ? (x + ti*8) : 32;
            __syncthreads();
            for (int i = tid; i < 2560; i += 512){
                int k = i >> 2, q = i & 3;
                const float* jp = &jl[(size_t)k*128 + bh*16 + q*4];
                st4[i] = make_float4(vld(jp+0), vld(jp+1), vld(jp+2), vld(jp+3));
            }
            __syncthreads();
            const int cg = tid & 31, bg = (tid>>5) & 3, kq = tid >> 7;
            const int c0 = tile*128 + cg*4;
            float acc[4][4];
            #pragma unroll
            for (int i2=0;i2<4;++i2)
                #pragma unroll
                for (int j2=0;j2<4;++j2) acc[i2][j2]=0.f;
            #pragma unroll 4
            for (int k = kq*160; k < kq*160+160; ++k){
                float4 w4 = *reinterpret_cast<const float4*>(&WoutTr[(size_t)k*VP3 + c0]);
                float4 h4 = st4[k*4 + bg];
                acc[0][0]=fmaf(w4.x,h4.x,acc[0][0]); acc[0][1]=fmaf(w4.x,h4.y,acc[0][1]);
                acc[0][2]=fmaf(w4.x,h4.z,acc[0][2]); acc[0][3]=fmaf(w4.x,h4.w,acc[0][3]);
                acc[1][0]=fmaf(w4.y,h4.x,acc[1][0]); acc[1][1]=fmaf(w4.y,h4.y,acc[1][1]);
                acc[1][2]=fmaf(w4.y,h4.z,acc[1][2]); acc[1][3]=fmaf(w4.y,h4.w,acc[1][3]);
                acc[2][0]=fmaf(w4.z,h4.x,acc[2][0]); acc[2][1]=fmaf(w4.z,h4.y,acc[2][1]);
                acc[2][2]=fmaf(w4.z,h4.z,acc[2][2]); acc[2][3]=fmaf(w4.z,h4.w,acc[2][3]);
                acc[3][0]=fmaf(w4.w,h4.x,acc[3][0]); acc[3][1]=fmaf(w4.w,h4.y,acc[3][1]);
                acc[3][2]=fmaf(w4.w,h4.z,acc[3][2]); acc[3][3]=fmaf(w4.w,h4.w,acc[3][3]);
            }
            int slot = tid & 127;
            if (kq > 0){
                #pragma unroll
                for (int i2=0;i2<4;++i2)
                    #pragma unroll
                    for (int j2=0;j2<4;++j2)
                        red[(kq-1)*2048 + slot*16 + i2*4+j2] = acc[i2][j2];
            }
            __syncthreads();
            if (kq == 0){
                #pragma unroll
                for (int j2=0;j2<4;++j2){
                    unsigned long long best = 0ULL;
                    #pragma unroll
                    for (int i2=0;i2<4;++i2){
                        float sv = acc[i2][j2] + red[slot*16 + i2*4+j2] + red[2048 + slot*16 + i2*4+j2]
                                 + red[4096 + slot*16 + i2*4+j2] + boutP[c0+i2];
                        unsigned long long kk = packkey(sv, (unsigned)(c0+i2));
                        if (kk > best) best = kk;
                    }
                    keysM[(bg*4+j2)*32 + cg] = best;
                }
            }
            __syncthreads();
            if (tid < 16){
                unsigned long long best = 0ULL;
                for (int q=0;q<32;++q){
                    unsigned long long kk = keysM[tid*32 + q];
                    if (kk > best) best = kk;
                }
                __hip_atomic_fetch_max(&slotW[x*128 + bh*16 + tid], best,
                                       __ATOMIC_RELAXED, __HIP_MEMORY_SCOPE_AGENT);
            }
            __syncthreads();
        }
        ++ph; xbar(arrL, lrelL, xdG, grG, x, r, R, ph, true);   // GLOBAL: slot+gates done
    }
}

// ---------------- final: emit t=511, hF, cF ----------------
__global__ __launch_bounds__(256) void kFin5(const int* __restrict__ lens,
                        const unsigned long long* __restrict__ slotX,
                        const float* __restrict__ hA, const float* __restrict__ hS,
                        const float* __restrict__ cA, const float* __restrict__ cB,
                        float* __restrict__ dout)
{
    int i = blockIdx.x*256 + threadIdx.x;
    if (i >= BB*HH) return;
    int b = i / HH, jj = i % HH;
    size_t o = (size_t)jj*128 + b;
    const unsigned long long* sl = slotX + ((TT-1)&1)*1024;
    unsigned long long key = 0ULL;
    #pragma unroll
    for (int y=0;y<8;++y){ unsigned long long v = sl[y*128+b]; if (v>key) key=v; }
    int k = (key==0ULL)?0:(int)(~(unsigned)key);
    bool m = ((TT-1) >= lens[b]) || (k == 0);
    dout[BB*TT + i]         = m ? hA[o] : hS[o];
    dout[BB*TT + BB*HH + i] = m ? cA[o] : cB[o];
    if (i < BB){
        unsigned long long key2 = 0ULL;
        #pragma unroll
        for (int y=0;y<8;++y){ unsigned long long v = sl[y*128+i]; if (v>key2) key2=v; }
        int k2 = (key2==0ULL)?0:(int)(~(unsigned)key2);
        bool mm = ((TT-1) >= lens[i]) || (k2 == 0);
        dout[(size_t)i*TT + (TT-1)] = mm ? 0.0f : (float)k2;
    }
}

// ================= fallback (small ws): basic per-step kernels =================
__global__ __launch_bounds__(256) void k_init(const float* __restrict__ h0, const float* __restrict__ c0,
                       float* __restrict__ hs0, float* __restrict__ cso,
                       int* __restrict__ label, unsigned long long* __restrict__ slot){
    int i = blockIdx.x*256 + threadIdx.x;
    if (i < BB*HH){ hs0[i] = h0[i]; cso[i] = c0[i]; }
    if (i < BB){ label[i] = 0; slot[i] = 0ULL; }
}

__global__ __launch_bounds__(256) void k_p1o(
    const float* __restrict__ Whh, const float* __restrict__ Wih,
    const float* __restrict__ embedding,
    const float* __restrict__ b_ih, const float* __restrict__ b_hh,
    const int* __restrict__ lens,
    const float* __restrict__ hs_r, float* __restrict__ hs_w,
    const float* __restrict__ h1_r, float* __restrict__ h1_w,
    float* c_state, float* c1o, int* label,
    const unsigned long long* __restrict__ slot,
    float* __restrict__ out_emit, int t)
{
    int tile = (blockIdx.x & 7)*20 + (blockIdx.x >> 3);
    int jt = tile >> 4, bg = tile & 15;
    int lane = threadIdx.x & 63, w = threadIdx.x >> 6;
    int j = (jt<<6) + lane, b0 = bg<<3;

    bool mask[8]; int kprev[8]; int sel[8];
    #pragma unroll
    for (int bi=0; bi<8; ++bi){
        int b = b0+bi;
        if (t == 0){ mask[bi]=true; sel[bi]=0; kprev[bi]=0; }
        else {
            unsigned long long key = slot[b];
            int k = (int)(~(unsigned)key);
            int lab = label[b];
            bool m = ((t-1) >= lens[b]) || (k == 0);
            mask[bi]=m; kprev[bi]=k; sel[bi] = m ? lab : k;
        }
    }
    float acc[8];
    #pragma unroll
    for (int i=0;i<8;i++) acc[i]=0.f;
    const float* wrow  = Whh + (size_t)(w*HH + j)*HH;
    const float* wrow2 = Wih + (size_t)(w*HH + j)*HH;
    for (int kc=0; kc<HH; kc+=16){
        float wv[16], wv2[16];
        #pragma unroll
        for (int q=0;q<4;q++){
            float4 f = *reinterpret_cast<const float4*>(wrow + kc + q*4);
            wv[q*4+0]=f.x; wv[q*4+1]=f.y; wv[q*4+2]=f.z; wv[q*4+3]=f.w;
            float4 f2 = *reinterpret_cast<const float4*>(wrow2 + kc + q*4);
            wv2[q*4+0]=f2.x; wv2[q*4+1]=f2.y; wv2[q*4+2]=f2.z; wv2[q*4+3]=f2.w;
        }
        #pragma unroll
        for (int bi=0; bi<8; ++bi){
            int b = b0+bi;
            const float* hp0 = hs_r + (size_t)b*HH + kc;
            const float* hp1 = h1_r + (size_t)b*HH + kc;
            float a = acc[bi];
            if (mask[bi]){
                #pragma unroll
                for (int k=0;k<16;k++) a = fmaf(hp0[k], wv[k], a);
            } else {
                #pragma unroll
                for (int k=0;k<16;k++) a = fmaf(hp1[k], wv[k], a);
            }
            if (t > 0){
                const float* ep = embedding + (size_t)sel[bi]*HH + kc;
                #pragma unroll
                for (int k=0;k<16;k++) a = fmaf(ep[k], wv2[k], a);
            }
            acc[bi] = a;
        }
    }
    __shared__ float xch[8][4][64];
    #pragma unroll
    for (int bi=0; bi<8; ++bi)
        xch[bi][w][lane] = acc[bi] + b_ih[w*HH + j] + b_hh[w*HH + j];
    __syncthreads();
    #pragma unroll
    for (int rr=0; rr<2; ++rr){
        int bi = (w<<1) + rr;
        int b  = b0 + bi;
        size_t o = (size_t)b*HH + j;
        float gi = xch[bi][0][lane], gf = xch[bi][1][lane];
        float gg = xch[bi][2][lane], go = xch[bi][3][lane];
        float ce = mask[bi] ? c_state[o] : c1o[o];
        float c2 = sigm(gf)*ce + sigm(gi)*tanhf(gg);
        float h2 = sigm(go)*tanhf(c2);
        float he = mask[bi] ? hs_r[o] : h1_r[o];
        c_state[o] = ce; c1o[o] = c2; hs_w[o] = he; h1_w[o] = h2;
    }
    if (jt == 0 && t > 0 && threadIdx.x < 8){
        int bi = threadIdx.x; int b = b0 + bi;
        out_emit[(size_t)b*TT + (t-1)] = mask[bi] ? 0.0f : (float)kprev[bi];
        label[b] = sel[bi];
    }
}

__global__ __launch_bounds__(128) void k_p2o(
    const float* __restrict__ Wpred, const float* __restrict__ Wenc,
    const float* __restrict__ x, const float* __restrict__ b_enc,
    const float* __restrict__ b_pred, const float* __restrict__ h1,
    float* __restrict__ joint, unsigned long long* __restrict__ slot, int t)
{
    int tile = (blockIdx.x & 7)*20 + (blockIdx.x >> 3);
    int nt = tile / 32, bg = tile % 32;
    int lane = threadIdx.x & 63, w = threadIdx.x >> 6;
    int n = nt*128 + w*64 + lane, b0 = bg*4;
    float acc[4] = {0.f,0.f,0.f,0.f};
    const float* wr  = Wpred + (size_t)n*HH;
    const float* wr2 = Wenc  + (size_t)n*HH;
    for (int kc=0; kc<HH; kc+=16){
        float wv[16], wv2[16];
        #pragma unroll
        for (int q=0;q<4;q++){
            float4 f = *reinterpret_cast<const float4*>(wr + kc + q*4);
            wv[q*4+0]=f.x; wv[q*4+1]=f.y; wv[q*4+2]=f.z; wv[q*4+3]=f.w;
            float4 f2 = *reinterpret_cast<const float4*>(wr2 + kc + q*4);
            wv2[q*4+0]=f2.x; wv2[q*4+1]=f2.y; wv2[q*4+2]=f2.z; wv2[q*4+3]=f2.w;
        }
        #pragma unroll
        for (int bi=0; bi<4; ++bi){
            int b = b0+bi;
            const float* hp = h1 + (size_t)b*HH + kc;
            float a = acc[bi];
            #pragma unroll
            for (int k=0;k<16;k++) a = fmaf(hp[k], wv[k], a);
            const float* xp = x + (size_t)b*HH*TT + (size_t)kc*TT + t;
            #pragma unroll
            for (int k=0;k<16;k++) a = fmaf(xp[(size_t)k*TT], wv2[k], a);
            acc[bi] = a;
        }
    }
    #pragma unroll
    for (int bi=0; bi<4; ++bi){
        int b = b0+bi;
        joint[(size_t)b*HH + n] = fmaxf(acc[bi] + b_pred[n] + b_enc[n], 0.0f);
    }
    if (tile == 0) slot[threadIdx.x] = 0ULL;
}

__global__ __launch_bounds__(256) void k_p3o(
    const float* __restrict__ Wout, const float* __restrict__ b_out,
    const float* __restrict__ joint, unsigned long long* __restrict__ slot)
{
    int tile = (blockIdx.x & 7)*34 + (blockIdx.x >> 3);
    int vt = tile >> 4, bg = tile & 15;
    int lane = threadIdx.x & 63, w = threadIdx.x >> 6;
    int v = vt*256 + w*64 + lane;
    bool valid = v < VV;
    int vv = valid ? v : (VV-1);
    int b0 = bg*8;
    float acc[8];
    #pragma unroll
    for (int i=0;i<8;i++) acc[i]=0.f;
    const float* wr = Wout + (size_t)vv*HH;
    for (int kc=0; kc<HH; kc+=16){
        float wv[16];
        #pragma unroll
        for (int q=0;q<4;q++){
            float4 f = *reinterpret_cast<const float4*>(wr + kc + q*4);
            wv[q*4+0]=f.x; wv[q*4+1]=f.y; wv[q*4+2]=f.z; wv[q*4+3]=f.w;
        }
        #pragma unroll
        for (int bi=0; bi<8; ++bi){
            int b = b0+bi;
            const float* jp = joint + (size_t)b*HH + kc;
            float a = acc[bi];
            #pragma unroll
            for (int k=0;k<16;k++) a = fmaf(jp[k], wv[k], a);
            acc[bi] = a;
        }
    }
    float bofl = b_out[vv];
    __shared__ unsigned long long redo[4][8];
    #pragma unroll
    for (int bi=0; bi<8; ++bi){
        unsigned long long key = valid ? packkey(acc[bi] + bofl, (unsigned)v) : 0ULL;
        #pragma unroll
        for (int off=32; off>0; off>>=1){
            unsigned long long o = __shfl_xor(key, off, 64);
            if (o > key) key = o;
        }
        if (lane == 0) redo[w][bi] = key;
    }
    __syncthreads();
    if (threadIdx.x < 8){
        int bi = threadIdx.x;
        unsigned long long m = redo[0][bi];
        #pragma unroll
        for (int q=1;q<4;q++) if (redo[q][bi] > m) m = redo[q][bi];
        atomicMax(&slot[b0+bi], m);
    }
}

__global__ __launch_bounds__(256) void k_finalo(const int* __restrict__ lens,
                        const unsigned long long* __restrict__ slot,
                        const float* __restrict__ hs_r, const float* __restrict__ h1_r,
                        const float* __restrict__ cso,  const float* __restrict__ c1o,
                        float* __restrict__ dout)
{
    int i = blockIdx.x*256 + threadIdx.x;
    if (i >= BB*HH) return;
    int b = i / HH;
    unsigned long long key = slot[b];
    int k = (int)(~(unsigned)key);
    bool m = ((TT-1) >= lens[b]) || (k == 0);
    dout[BB*TT + i]         = m ? hs_r[i] : h1_r[i];
    dout[BB*TT + BB*HH + i] = m ? cso[i]  : c1o[i];
    if (i < BB){
        unsigned long long key2 = slot[i];
        int k2 = (int)(~(unsigned)key2);
        bool mm = ((TT-1) >= lens[i]) || (k2 == 0);
        dout[(size_t)i*TT + (TT-1)] = mm ? 0.0f : (float)k2;
    }
}

extern "C" void kernel_launch(void* const* d_in, const int* in_sizes, int n_in,
                              void* d_out, int out_size, void* d_ws, size_t ws_size,
                              hipStream_t stream)
{
    const float* x     = (const float*)d_in[0];
    const int*   lens  = (const int*)  d_in[1];
    const float* emb   = (const float*)d_in[2];
    const float* Wih   = (const float*)d_in[3];
    const float* Whh   = (const float*)d_in[4];
    const float* bih   = (const float*)d_in[5];
    const float* bhh   = (const float*)d_in[6];
    const float* Wenc  = (const float*)d_in[7];
    const float* benc  = (const float*)d_in[8];
    const float* Wpred = (const float*)d_in[9];
    const float* bpred = (const float*)d_in[10];
    const float* Wout  = (const float*)d_in[11];
    const float* bout  = (const float*)d_in[12];
    const float* h0    = (const float*)d_in[13];
    const float* c0    = (const float*)d_in[14];
    float* out = (float*)d_out;
    (void)in_sizes; (void)n_in; (void)out_size;

    char* ws = (char*)d_ws;
    size_t off = 0;
    auto alloc = [&](size_t bytes) -> void* {
        void* p = ws + off; off += (bytes + 255) & ~(size_t)255; return p;
    };
    const size_t SSZ = (size_t)XSZ*sizeof(float);       // 0.33MB
    float* gA  = (float*)alloc(SSZ*4);
    float* gB  = (float*)alloc(SSZ*4);
    float* cA  = (float*)alloc(SSZ);
    float* cB  = (float*)alloc(SSZ);
    float* hA  = (float*)alloc(SSZ);
    float* hS  = (float*)alloc(SSZ);
    float* jlp = (float*)alloc(8*SSZ);
    unsigned long long* slotX = (unsigned long long*)alloc(2048*sizeof(unsigned long long));
    int* labelp = (int*)alloc(1024*sizeof(int));
    int* ctrl   = (int*)alloc(8192*sizeof(int));
    float* boutP = (float*)alloc((size_t)VP3*sizeof(float));
    float* WhhT  = (float*)alloc((size_t)HH*G4*sizeof(float));   // persistent
    float* WpredT= (float*)alloc((size_t)HH*HH*sizeof(float));   // persistent
    float* WoutTr= (float*)alloc((size_t)HH*VP3*sizeof(float));  // persistent
    float* WihT  = (float*)alloc((size_t)HH*G4*sizeof(float));   // temp
    float* WencT = (float*)alloc((size_t)HH*HH*sizeof(float));   // temp
    float* embproj  = (float*)alloc((size_t)(VV+1)*G4*sizeof(float));
    float* encprojT = (float*)alloc((size_t)TT*BB*HH*sizeof(float));
    size_t need = off;

    if (ws_size >= need){
        k_init7<<<(BB*HH+255)/256, 256, 0, stream>>>(h0, c0, hA, cA, hS, labelp, slotX, ctrl);
        k_tr_gate<<<(G4*160+255)/256, 256, 0, stream>>>(Whh, WhhT);
        k_tr_gate<<<(G4*160+255)/256, 256, 0, stream>>>(Wih, WihT);
        k_tr640<<<(HH*160+255)/256, 256, 0, stream>>>(Wpred, WpredT);
        k_tr640<<<(HH*160+255)/256, 256, 0, stream>>>(Wenc, WencT);
        k_tr_woutr<<<(VP3*160+255)/256, 256, 0, stream>>>(Wout, WoutTr);
        k_boutp<<<(VP3+255)/256, 256, 0, stream>>>(bout, boutP);
        k_embproj2<<<17*160, 256, 0, stream>>>(emb, WihT, bih, bhh, embproj);
        k_encprojT2<<<20480, 128, 0, stream>>>(x, WencT, benc, encprojT);
        k_gA02<<<(G4*BB+255)/256, 256, 0, stream>>>(WhhT, hS, gA);

        const float* a0 = WhhT;   const float* a1 = WpredT;
        const float* a2 = WoutTr; const float* a3 = bpred;
        const float* a4 = boutP;  const float* a5 = embproj;
        const float* a6 = encprojT; const int* a7 = lens;
        float* a8 = gA; float* a9 = gB; float* a10 = cA; float* a11 = cB;
        float* a12 = hA; float* a13 = hS; float* a14 = jlp;
        unsigned long long* a15 = slotX; int* a16 = labelp;
        int* a17 = ctrl; float* a18 = out;
        void* args[] = {&a0,&a1,&a2,&a3,&a4,&a5,&a6,&a7,&a8,&a9,&a10,&a11,
                        &a12,&a13,&a14,&a15,&a16,&a17,&a18};
        (void)hipLaunchCooperativeKernel((const void*)k_run4, dim3(256), dim3(512), args, 0, stream);
        kFin5<<<(BB*HH+255)/256, 256, 0, stream>>>(lens, slotX, hA, hS, cA, cB, out);
        return;
    }

    // -------- fallback: basic per-step path (small ws) --------
    {
        size_t foff = 0;
        auto falloc = [&](size_t bytes) -> void* {
            void* p = ws + foff; foff += (bytes + 255) & ~(size_t)255; return p;
        };
        const size_t BH = (size_t)BB*HH*sizeof(float);
        float* hs0  = (float*)falloc(BH);
        float* hs1  = (float*)falloc(BH);
        float* h1b0 = (float*)falloc(BH);
        float* h1b1 = (float*)falloc(BH);
        float* cso  = (float*)falloc(BH);
        float* c1o  = (float*)falloc(BH);
        float* joint= (float*)falloc(BH);
        int* labelf = (int*)falloc(BB*sizeof(int));
        unsigned long long* slotf = (unsigned long long*)falloc(BB*sizeof(unsigned long long));

        k_init<<<(BB*HH+255)/256, 256, 0, stream>>>(h0, c0, hs0, cso, labelf, slotf);
        float* hsbuf[2] = {hs0, hs1};
        float* h1buf[2] = {h1b0, h1b1};
        for (int t = 0; t < TT; ++t){
            const float* hsr = hsbuf[t & 1];
            float*       hsw = hsbuf[(t+1) & 1];
            const float* h1r = h1buf[(t+1) & 1];
            float*       h1w = h1buf[t & 1];
            k_p1o<<<160, 256, 0, stream>>>(Whh, Wih, emb, bih, bhh, lens,
                                           hsr, hsw, h1r, h1w, cso, c1o, labelf, slotf, out, t);
            k_p2o<<<160, 128, 0, stream>>>(Wpred, Wenc, x, benc, bpred, h1w, joint, slotf, t);
            k_p3o<<<272, 256, 0, stream>>>(Wout, bout, joint, slotf);
        }
        k_finalo<<<(BB*HH+255)/256, 256, 0, stream>>>(lens, slotf, hsbuf[0], h1buf[1], cso, c1o, out);
    }
}

// Round 11
// 30093.784 us; speedup vs baseline: 3.8761x; 3.8761x over previous
//
#include <hip/hip_runtime.h>
#include <stdint.h>

#define HH 640
#define BB 128
#define TT 512
#define VV 4097
#define G4 2560
#define VP3 4352   // 272*16 padded vocab

typedef float f32x4v __attribute__((ext_vector_type(4)));

__device__ __forceinline__ float sigm(float x){ return 1.0f/(1.0f+expf(-x)); }

// monotonic packed key: larger logit wins; ties -> smaller v (jnp.argmax first-index)
__device__ __forceinline__ unsigned long long packkey(float f, unsigned v){
    unsigned u = __float_as_uint(f);
    unsigned m = (u & 0x80000000u) ? ~u : (u | 0x80000000u);
    return ((unsigned long long)m << 32) | (unsigned long long)(~v);
}
__device__ __forceinline__ int xcd_tile(int bid, int per){ return (bid & 7)*per + (bid >> 3); }
// transposed state addressing: [k>>2][b][k&3]
__device__ __forceinline__ size_t taddr(int k, int b){
    return ((size_t)(k>>2)*BB + b)*4 + (k&3);
}

// ---------------- init (transposed state) ----------------
__global__ __launch_bounds__(256) void k_init3(const float* __restrict__ h0, const float* __restrict__ c0,
                       float* __restrict__ hs0, float* __restrict__ csT,
                       int* __restrict__ label, unsigned long long* __restrict__ slot8){
    int i = blockIdx.x*256 + threadIdx.x;
    if (i < BB*HH){
        int b = i / HH, jj = i % HH;
        size_t o = taddr(jj, b);
        hs0[o] = h0[i]; csT[o] = c0[i];
    }
    if (i < BB) label[i] = 0;
    if (i < 8*BB) slot8[i] = 0ULL;
}

// ---------------- one-time transposes ----------------
__global__ __launch_bounds__(256) void k_tr_gate(const float* __restrict__ W, float* __restrict__ WT){
    int idx = blockIdx.x*256 + threadIdx.x;
    if (idx >= G4*160) return;
    int row = idx / 160, kq = idx % 160;
    int g = row / HH, jj = row % HH;
    float4 f = *reinterpret_cast<const float4*>(W + (size_t)row*HH + kq*4);
    WT[(size_t)(kq*4+0)*G4 + jj*4+g] = f.x;
    WT[(size_t)(kq*4+1)*G4 + jj*4+g] = f.y;
    WT[(size_t)(kq*4+2)*G4 + jj*4+g] = f.z;
    WT[(size_t)(kq*4+3)*G4 + jj*4+g] = f.w;
}
__global__ __launch_bounds__(256) void k_tr640(const float* __restrict__ W, float* __restrict__ WT){
    int idx = blockIdx.x*256 + threadIdx.x;
    if (idx >= HH*160) return;
    int n = idx / 160, kq = idx % 160;
    float4 f = *reinterpret_cast<const float4*>(W + (size_t)n*HH + kq*4);
    WT[(size_t)(kq*4+0)*HH + n] = f.x;
    WT[(size_t)(kq*4+1)*HH + n] = f.y;
    WT[(size_t)(kq*4+2)*HH + n] = f.z;
    WT[(size_t)(kq*4+3)*HH + n] = f.w;
}
__global__ __launch_bounds__(256) void k_tr_woutr(const float* __restrict__ W, float* __restrict__ WT){
    int idx = blockIdx.x*256 + threadIdx.x;
    if (idx >= VP3*160) return;
    int v = idx / 160, kq = idx % 160;
    float4 f = make_float4(0.f,0.f,0.f,0.f);
    if (v < VV) f = *reinterpret_cast<const float4*>(W + (size_t)v*HH + kq*4);
    WT[(size_t)(kq*4+0)*VP3 + v] = f.x;
    WT[(size_t)(kq*4+1)*VP3 + v] = f.y;
    WT[(size_t)(kq*4+2)*VP3 + v] = f.z;
    WT[(size_t)(kq*4+3)*VP3 + v] = f.w;
}
__global__ __launch_bounds__(256) void k_boutp(const float* __restrict__ b_out, float* __restrict__ bp){
    int v = blockIdx.x*256 + threadIdx.x;
    if (v < VP3) bp[v] = (v < VV) ? b_out[v] : -1e30f;
}

// ---------------- per-block contiguous weight packs ----------------
// WhhP[bid][k][16] <- WhhT[k*G4 + bid*16 + ...]
__global__ __launch_bounds__(256) void k_packA(const float* __restrict__ WhhT, float* __restrict__ WhhP){
    int i = blockIdx.x*256 + threadIdx.x;      // granules: 160*640*4
    if (i >= 160*HH*4) return;
    int bid = i / (HH*4), rem = i % (HH*4);
    int k = rem >> 2, q = rem & 3;
    reinterpret_cast<float4*>(WhhP)[i] =
        *reinterpret_cast<const float4*>(&WhhT[(size_t)k*G4 + bid*16 + q*4]);
}
// WpredP[bid][k][4]
__global__ __launch_bounds__(256) void k_packB(const float* __restrict__ WpredT, float* __restrict__ WpredP){
    int i = blockIdx.x*256 + threadIdx.x;      // granules: 160*640
    if (i >= 160*HH) return;
    int bid = i / HH, k = i % HH;
    reinterpret_cast<float4*>(WpredP)[i] =
        *reinterpret_cast<const float4*>(&WpredT[(size_t)k*HH + bid*4]);
}
// WoutP[bid][k][16]
__global__ __launch_bounds__(256) void k_packC(const float* __restrict__ WoutTr, float* __restrict__ WoutP){
    int i = blockIdx.x*256 + threadIdx.x;      // granules: 272*640*4
    if (i >= 272*HH*4) return;
    int bid = i / (HH*4), rem = i % (HH*4);
    int k = rem >> 2, q = rem & 3;
    reinterpret_cast<float4*>(WoutP)[i] =
        *reinterpret_cast<const float4*>(&WoutTr[(size_t)k*VP3 + bid*16 + q*4]);
}

// ---------------- emb_proj: [VV+1][2560] gate-interleaved; row VV = bias-only ----------------
__global__ __launch_bounds__(256) void k_embproj2(const float* __restrict__ emb,
                          const float* __restrict__ WihT,
                          const float* __restrict__ b_ih, const float* __restrict__ b_hh,
                          float* __restrict__ embproj){
    __shared__ float lw[640*16];
    int vt = blockIdx.x / 160, ut = blockIdx.x % 160;
    for (int i=threadIdx.x; i<640*16; i+=256)
        lw[i] = WihT[(size_t)(i>>4)*G4 + ut*16 + (i&15)];
    float bias[16];
    #pragma unroll
    for (int u=0;u<16;++u){
        int gu = ut*16+u, jj = gu>>2, g = gu&3;
        bias[u] = b_ih[g*HH+jj] + b_hh[g*HH+jj];
    }
    __syncthreads();
    int v = vt*256 + threadIdx.x;
    float acc[16];
    #pragma unroll
    for (int u=0;u<16;++u) acc[u]=0.f;
    if (v < VV){
        const float4* er = reinterpret_cast<const float4*>(emb + (size_t)v*HH);
        for (int k4=0;k4<160;++k4){
            float4 ev = er[k4];
            #pragma unroll
            for (int q=0;q<4;++q){
                float e = (q==0)?ev.x:(q==1)?ev.y:(q==2)?ev.z:ev.w;
                const f32x4v* wr = reinterpret_cast<const f32x4v*>(&lw[(k4*4+q)*16]);
                #pragma unroll
                for (int g=0; g<4; ++g){
                    f32x4v w = wr[g];
                    #pragma unroll
                    for (int ee=0; ee<4; ++ee) acc[g*4+ee] = fmaf(w[ee], e, acc[g*4+ee]);
                }
            }
        }
    }
    if (v <= VV){
        #pragma unroll
        for (int q=0;q<4;++q){
            float4 st = make_float4(acc[q*4+0]+bias[q*4+0], acc[q*4+1]+bias[q*4+1],
                                    acc[q*4+2]+bias[q*4+2], acc[q*4+3]+bias[q*4+3]);
            *reinterpret_cast<float4*>(embproj + (size_t)v*G4 + ut*16 + q*4) = st;
        }
    }
}

// ---------------- enc_proj precompute, layout [t][n][b] ----------------
__global__ __launch_bounds__(128) void k_encprojT2(const float* __restrict__ x,
                          const float* __restrict__ WencT, const float* __restrict__ b_enc,
                          float* __restrict__ encprojT){
    int tile = (blockIdx.x & 7)*2560 + (blockIdx.x >> 3);
    int b   = tile / 160;
    int rem = tile % 160;
    int tt  = rem / 5;
    int nt2 = rem % 5;
    int n = nt2*128 + threadIdx.x;
    float acc[16];
    #pragma unroll
    for (int i=0;i<16;i++) acc[i]=0.f;
    const float* xb = x + (size_t)b*HH*TT + tt*16;
    #pragma unroll 4
    for (int k=0;k<HH;++k){
        float wv = WencT[(size_t)k*HH + n];
        const float4* xp = reinterpret_cast<const float4*>(xb + (size_t)k*TT);
        float4 x0=xp[0], x1=xp[1], x2=xp[2], x3=xp[3];
        acc[0]=fmaf(x0.x,wv,acc[0]);  acc[1]=fmaf(x0.y,wv,acc[1]);
        acc[2]=fmaf(x0.z,wv,acc[2]);  acc[3]=fmaf(x0.w,wv,acc[3]);
        acc[4]=fmaf(x1.x,wv,acc[4]);  acc[5]=fmaf(x1.y,wv,acc[5]);
        acc[6]=fmaf(x1.z,wv,acc[6]);  acc[7]=fmaf(x1.w,wv,acc[7]);
        acc[8]=fmaf(x2.x,wv,acc[8]);  acc[9]=fmaf(x2.y,wv,acc[9]);
        acc[10]=fmaf(x2.z,wv,acc[10]); acc[11]=fmaf(x2.w,wv,acc[11]);
        acc[12]=fmaf(x3.x,wv,acc[12]); acc[13]=fmaf(x3.y,wv,acc[13]);
        acc[14]=fmaf(x3.z,wv,acc[14]); acc[15]=fmaf(x3.w,wv,acc[15]);
    }
    float be = b_enc[n];
    #pragma unroll
    for (int ti=0; ti<16; ++ti)
        encprojT[((size_t)(tt*16+ti)*HH + n)*BB + b] = acc[ti] + be;
}

// ================= per-step kernels (champion R5 structure, packed weights) =================

// ---- A: gates GEMM + LSTM nonlin + lazy commit of t-1 ----
__global__ __launch_bounds__(512) void kA(
    const float* __restrict__ WhhP, const float* __restrict__ embproj,
    const int* __restrict__ lens,
    const float* __restrict__ hsrT, float* __restrict__ hswT,
    const float* __restrict__ h1rT, float* __restrict__ h1wT,
    float* __restrict__ csT, float* __restrict__ c1T,
    int* __restrict__ label, const unsigned long long* __restrict__ slot8,
    float* __restrict__ out_emit, int t)
{
    __shared__ float lw[HH*16];        // 41 KB
    __shared__ float red[3*16*128];    // 24.6 KB
    const int bid = xcd_tile(blockIdx.x, 20);   // 160 blocks, 16 gate-units each
    const int tid = threadIdx.x;
    const int b = tid & 127, kh = tid >> 7;
    const int u0 = bid*16;

    {
        const float4* wsrc = reinterpret_cast<const float4*>(WhhP + (size_t)bid*(HH*16));
        float4* ld = reinterpret_cast<float4*>(lw);
        for (int i=tid; i<HH*4; i+=512) ld[i] = wsrc[i];
    }

    bool mask; int sel=0, kprev=0;
    if (t==0){ mask=true; sel=0; }
    else{
        unsigned long long key = slot8[b];
        #pragma unroll
        for (int q=1;q<8;++q){ unsigned long long o=slot8[q*128+b]; if(o>key)key=o; }
        int k = (int)(~(unsigned)key);
        int lab = label[b];
        mask = ((t-1) >= lens[b]) || (k==0);
        kprev = k; sel = mask ? lab : k;
    }
    __syncthreads();

    const float4* hp = reinterpret_cast<const float4*>(mask ? hsrT : h1rT);
    float a1[16];
    #pragma unroll
    for (int u=0;u<16;++u) a1[u]=0.f;
    const int k0 = kh*40;
    #pragma unroll 4
    for (int k4=k0; k4<k0+40; ++k4){
        float4 hv = hp[(size_t)k4*BB + b];
        #pragma unroll
        for (int q=0;q<4;++q){
            float h = (q==0)?hv.x:(q==1)?hv.y:(q==2)?hv.z:hv.w;
            const f32x4v* wr = reinterpret_cast<const f32x4v*>(&lw[(k4*4+q)*16]);
            #pragma unroll
            for (int g=0; g<4; ++g){
                f32x4v w = wr[g];
                #pragma unroll
                for (int ee=0; ee<4; ++ee) a1[g*4+ee] = fmaf(w[ee], h, a1[g*4+ee]);
            }
        }
    }
    if (kh > 0){
        #pragma unroll
        for (int u=0;u<16;++u) red[((kh-1)*16+u)*128 + b] = a1[u];
    }
    __syncthreads();
    if (kh == 0){
        int erow = (t==0) ? VV : sel;
        const float4* eb = reinterpret_cast<const float4*>(embproj + (size_t)erow*G4 + u0);
        const size_t g4 = (size_t)bid*BB + b;   // float4 granule (units bid*4..+3)
        float4 ce4 = mask ? reinterpret_cast<const float4*>(csT)[g4]
                          : reinterpret_cast<const float4*>(c1T)[g4];
        float4 he4 = mask ? reinterpret_cast<const float4*>(hsrT)[g4]
                          : reinterpret_cast<const float4*>(h1rT)[g4];
        float cn[4], hn[4];
        const float* cep = &ce4.x;
        #pragma unroll
        for (int jl=0; jl<4; ++jl){
            float4 e = eb[jl];
            float gi = a1[jl*4+0] + red[(jl*4+0)*128+b] + red[(16+jl*4+0)*128+b] + red[(32+jl*4+0)*128+b] + e.x;
            float gf = a1[jl*4+1] + red[(jl*4+1)*128+b] + red[(16+jl*4+1)*128+b] + red[(32+jl*4+1)*128+b] + e.y;
            float gg = a1[jl*4+2] + red[(jl*4+2)*128+b] + red[(16+jl*4+2)*128+b] + red[(32+jl*4+2)*128+b] + e.z;
            float go = a1[jl*4+3] + red[(jl*4+3)*128+b] + red[(16+jl*4+3)*128+b] + red[(32+jl*4+3)*128+b] + e.w;
            float ce = cep[jl];
            float cv = sigm(gf)*ce + sigm(gi)*tanhf(gg);
            cn[jl] = cv;
            hn[jl] = sigm(go)*tanhf(cv);
        }
        reinterpret_cast<float4*>(csT)[g4]  = ce4;                                  // committed thru t-1
        reinterpret_cast<float4*>(c1T)[g4]  = make_float4(cn[0],cn[1],cn[2],cn[3]); // tentative t
        reinterpret_cast<float4*>(hswT)[g4] = he4;
        reinterpret_cast<float4*>(h1wT)[g4] = make_float4(hn[0],hn[1],hn[2],hn[3]);
        if (bid == 0){
            if (t > 0) out_emit[(size_t)b*TT + (t-1)] = mask ? 0.f : (float)kprev;
            label[b] = sel;   // idempotent-select race-safe
        }
    }
}

// ---- B: joint = relu(h1@WpredT + b_pred + encprojT[t]) ; reset slots ----
__global__ __launch_bounds__(512) void kB(
    const float* __restrict__ WpredP, const float* __restrict__ encprojT,
    const float* __restrict__ b_pred, const float* __restrict__ h1T,
    float* __restrict__ jointT, unsigned long long* __restrict__ slot8, int t)
{
    __shared__ float lw[HH*4];        // 10.2 KB
    __shared__ float red[3*4*128];    // 6.1 KB
    const int bid = xcd_tile(blockIdx.x, 20);   // 160 blocks, 4 n each
    const int tid = threadIdx.x;
    const int b = tid & 127, kh = tid >> 7;
    const int n0 = bid*4;
    {
        const float4* wsrc = reinterpret_cast<const float4*>(WpredP + (size_t)bid*(HH*4));
        float4* ld = reinterpret_cast<float4*>(lw);
        for (int i=tid; i<HH; i+=512) ld[i] = wsrc[i];
    }
    if (bid == 0 && kh == 3){   // reset slots (A consumed them; C refills)
        #pragma unroll
        for (int q=0;q<8;++q) slot8[q*128 + b] = 0ULL;
    }
    __syncthreads();
    const float4* hp = reinterpret_cast<const float4*>(h1T);
    float a[4] = {0.f,0.f,0.f,0.f};
    const int k0 = kh*40;
    #pragma unroll 4
    for (int k4=k0; k4<k0+40; ++k4){
        float4 hv = hp[(size_t)k4*BB + b];
        #pragma unroll
        for (int q=0;q<4;++q){
            float h = (q==0)?hv.x:(q==1)?hv.y:(q==2)?hv.z:hv.w;
            f32x4v w = *reinterpret_cast<const f32x4v*>(&lw[(k4*4+q)*4]);
            #pragma unroll
            for (int ee=0; ee<4; ++ee) a[ee] = fmaf(w[ee], h, a[ee]);
        }
    }
    if (kh > 0){
        #pragma unroll
        for (int u=0;u<4;++u) red[((kh-1)*4+u)*128 + b] = a[u];
    }
    __syncthreads();
    if (kh == 0){
        float jn[4];
        #pragma unroll
        for (int u=0;u<4;++u){
            float s = a[u] + red[u*128+b] + red[(4+u)*128+b] + red[(8+u)*128+b]
                    + b_pred[n0+u] + encprojT[((size_t)t*HH + n0+u)*BB + b];
            jn[u] = fmaxf(s, 0.f);
        }
        reinterpret_cast<float4*>(jointT)[(size_t)bid*BB + b] =
            make_float4(jn[0],jn[1],jn[2],jn[3]);
    }
}

// ---- C: logits + argmax ----
__global__ __launch_bounds__(512) void kC(
    const float* __restrict__ WoutP, const float* __restrict__ boutP,
    const float* __restrict__ jointT, unsigned long long* __restrict__ slot8)
{
    __shared__ float lw[HH*16];        // 41 KB
    __shared__ float red[3*16*128];    // 24.6 KB
    const int bid = xcd_tile(blockIdx.x, 34);   // 272 blocks, 16 v each
    const int tid = threadIdx.x;
    const int b = tid & 127, kh = tid >> 7;
    const int v0 = bid*16;
    {
        const float4* wsrc = reinterpret_cast<const float4*>(WoutP + (size_t)bid*(HH*16));
        float4* ld = reinterpret_cast<float4*>(lw);
        for (int i=tid; i<HH*4; i+=512) ld[i] = wsrc[i];
    }
    __syncthreads();
    const float4* jp = reinterpret_cast<const float4*>(jointT);
    float a[16];
    #pragma unroll
    for (int u=0;u<16;++u) a[u]=0.f;
    const int k0 = kh*40;
    #pragma unroll 4
    for (int k4=k0; k4<k0+40; ++k4){
        float4 jv = jp[(size_t)k4*BB + b];
        #pragma unroll
        for (int q=0;q<4;++q){
            float h = (q==0)?jv.x:(q==1)?jv.y:(q==2)?jv.z:jv.w;
            const f32x4v* wr = reinterpret_cast<const f32x4v*>(&lw[(k4*4+q)*16]);
            #pragma unroll
            for (int g=0; g<4; ++g){
                f32x4v w = wr[g];
                #pragma unroll
                for (int ee=0; ee<4; ++ee) a[g*4+ee] = fmaf(w[ee], h, a[g*4+ee]);
            }
        }
    }
    if (kh > 0){
        #pragma unroll
        for (int u=0;u<16;++u) red[((kh-1)*16+u)*128 + b] = a[u];
    }
    __syncthreads();
    if (kh == 0){
        unsigned long long key = 0ULL;
        #pragma unroll
        for (int u=0;u<16;++u){
            float s = a[u] + red[u*128+b] + red[(16+u)*128+b] + red[(32+u)*128+b] + boutP[v0+u];
            unsigned long long kk = packkey(s, (unsigned)(v0+u));
            if (kk > key) key = kk;
        }
        atomicMax(&slot8[(bid&7)*128 + b], key);
    }
}

// ---- final: emit t=511, hF, cF ----
__global__ __launch_bounds__(256) void kFin(const int* __restrict__ lens,
                        const unsigned long long* __restrict__ slot8,
                        const float* __restrict__ hsT, const float* __restrict__ h1T,
                        const float* __restrict__ csT, const float* __restrict__ c1T,
                        float* __restrict__ dout)
{
    int i = blockIdx.x*256 + threadIdx.x;
    if (i >= BB*HH) return;
    int b = i / HH, jj = i % HH;
    unsigned long long key = slot8[b];
    #pragma unroll
    for (int q=1;q<8;++q){ unsigned long long o=slot8[q*128+b]; if(o>key)key=o; }
    int k = (int)(~(unsigned)key);
    bool m = ((TT-1) >= lens[b]) || (k == 0);
    size_t o = taddr(jj, b);
    dout[BB*TT + i]         = m ? hsT[o] : h1T[o];
    dout[BB*TT + BB*HH + i] = m ? csT[o] : c1T[o];
    if (i < BB){
        unsigned long long key2 = slot8[i];
        #pragma unroll
        for (int q=1;q<8;++q){ unsigned long long o2=slot8[q*128+i]; if(o2>key2)key2=o2; }
        int k2 = (int)(~(unsigned)key2);
        bool mm = ((TT-1) >= lens[i]) || (k2 == 0);
        dout[(size_t)i*TT + (TT-1)] = mm ? 0.0f : (float)k2;
    }
}

// ================= fallback (small ws): basic per-step kernels =================
__global__ __launch_bounds__(256) void k_init(const float* __restrict__ h0, const float* __restrict__ c0,
                       float* __restrict__ hs0, float* __restrict__ cso,
                       int* __restrict__ label, unsigned long long* __restrict__ slot){
    int i = blockIdx.x*256 + threadIdx.x;
    if (i < BB*HH){ hs0[i] = h0[i]; cso[i] = c0[i]; }
    if (i < BB){ label[i] = 0; slot[i] = 0ULL; }
}

__global__ __launch_bounds__(256) void k_p1o(
    const float* __restrict__ Whh, const float* __restrict__ Wih,
    const float* __restrict__ embedding,
    const float* __restrict__ b_ih, const float* __restrict__ b_hh,
    const int* __restrict__ lens,
    const float* __restrict__ hs_r, float* __restrict__ hs_w,
    const float* __restrict__ h1_r, float* __restrict__ h1_w,
    float* c_state, float* c1o, int* label,
    const unsigned long long* __restrict__ slot,
    float* __restrict__ out_emit, int t)
{
    int tile = (blockIdx.x & 7)*20 + (blockIdx.x >> 3);
    int jt = tile >> 4, bg = tile & 15;
    int lane = threadIdx.x & 63, w = threadIdx.x >> 6;
    int j = (jt<<6) + lane, b0 = bg<<3;

    bool mask[8]; int kprev[8]; int sel[8];
    #pragma unroll
    for (int bi=0; bi<8; ++bi){
        int b = b0+bi;
        if (t == 0){ mask[bi]=true; sel[bi]=0; kprev[bi]=0; }
        else {
            unsigned long long key = slot[b];
            int k = (int)(~(unsigned)key);
            int lab = label[b];
            bool m = ((t-1) >= lens[b]) || (k == 0);
            mask[bi]=m; kprev[bi]=k; sel[bi] = m ? lab : k;
        }
    }
    float acc[8];
    #pragma unroll
    for (int i=0;i<8;i++) acc[i]=0.f;
    const float* wrow  = Whh + (size_t)(w*HH + j)*HH;
    const float* wrow2 = Wih + (size_t)(w*HH + j)*HH;
    for (int kc=0; kc<HH; kc+=16){
        float wv[16], wv2[16];
        #pragma unroll
        for (int q=0;q<4;q++){
            float4 f = *reinterpret_cast<const float4*>(wrow + kc + q*4);
            wv[q*4+0]=f.x; wv[q*4+1]=f.y; wv[q*4+2]=f.z; wv[q*4+3]=f.w;
            float4 f2 = *reinterpret_cast<const float4*>(wrow2 + kc + q*4);
            wv2[q*4+0]=f2.x; wv2[q*4+1]=f2.y; wv2[q*4+2]=f2.z; wv2[q*4+3]=f2.w;
        }
        #pragma unroll
        for (int bi=0; bi<8; ++bi){
            int b = b0+bi;
            const float* hp0 = hs_r + (size_t)b*HH + kc;
            const float* hp1 = h1_r + (size_t)b*HH + kc;
            float a = acc[bi];
            if (mask[bi]){
                #pragma unroll
                for (int k=0;k<16;k++) a = fmaf(hp0[k], wv[k], a);
            } else {
                #pragma unroll
                for (int k=0;k<16;k++) a = fmaf(hp1[k], wv[k], a);
            }
            if (t > 0){
                const float* ep = embedding + (size_t)sel[bi]*HH + kc;
                #pragma unroll
                for (int k=0;k<16;k++) a = fmaf(ep[k], wv2[k], a);
            }
            acc[bi] = a;
        }
    }
    __shared__ float xch[8][4][64];
    #pragma unroll
    for (int bi=0; bi<8; ++bi)
        xch[bi][w][lane] = acc[bi] + b_ih[w*HH + j] + b_hh[w*HH + j];
    __syncthreads();
    #pragma unroll
    for (int rr=0; rr<2; ++rr){
        int bi = (w<<1) + rr;
        int b  = b0 + bi;
        size_t o = (size_t)b*HH + j;
        float gi = xch[bi][0][lane], gf = xch[bi][1][lane];
        float gg = xch[bi][2][lane], go = xch[bi][3][lane];
        float ce = mask[bi] ? c_state[o] : c1o[o];
        float c2 = sigm(gf)*ce + sigm(gi)*tanhf(gg);
        float h2 = sigm(go)*tanhf(c2);
        float he = mask[bi] ? hs_r[o] : h1_r[o];
        c_state[o] = ce; c1o[o] = c2; hs_w[o] = he; h1_w[o] = h2;
    }
    if (jt == 0 && t > 0 && threadIdx.x < 8){
        int bi = threadIdx.x; int b = b0 + bi;
        out_emit[(size_t)b*TT + (t-1)] = mask[bi] ? 0.0f : (float)kprev[bi];
        label[b] = sel[bi];
    }
}

__global__ __launch_bounds__(128) void k_p2o(
    const float* __restrict__ Wpred, const float* __restrict__ Wenc,
    const float* __restrict__ x, const float* __restrict__ b_enc,
    const float* __restrict__ b_pred, const float* __restrict__ h1,
    float* __restrict__ joint, unsigned long long* __restrict__ slot, int t)
{
    int tile = (blockIdx.x & 7)*20 + (blockIdx.x >> 3);
    int nt = tile / 32, bg = tile % 32;
    int lane = threadIdx.x & 63, w = threadIdx.x >> 6;
    int n = nt*128 + w*64 + lane, b0 = bg*4;
    float acc[4] = {0.f,0.f,0.f,0.f};
    const float* wr  = Wpred + (size_t)n*HH;
    const float* wr2 = Wenc  + (size_t)n*HH;
    for (int kc=0; kc<HH; kc+=16){
        float wv[16], wv2[16];
        #pragma unroll
        for (int q=0;q<4;q++){
            float4 f = *reinterpret_cast<const float4*>(wr + kc + q*4);
            wv[q*4+0]=f.x; wv[q*4+1]=f.y; wv[q*4+2]=f.z; wv[q*4+3]=f.w;
            float4 f2 = *reinterpret_cast<const float4*>(wr2 + kc + q*4);
            wv2[q*4+0]=f2.x; wv2[q*4+1]=f2.y; wv2[q*4+2]=f2.z; wv2[q*4+3]=f2.w;
        }
        #pragma unroll
        for (int bi=0; bi<4; ++bi){
            int b = b0+bi;
            const float* hp = h1 + (size_t)b*HH + kc;
            float a = acc[bi];
            #pragma unroll
            for (int k=0;k<16;k++) a = fmaf(hp[k], wv[k], a);
            const float* xp = x + (size_t)b*HH*TT + (size_t)kc*TT + t;
            #pragma unroll
            for (int k=0;k<16;k++) a = fmaf(xp[(size_t)k*TT], wv2[k], a);
            acc[bi] = a;
        }
    }
    #pragma unroll
    for (int bi=0; bi<4; ++bi){
        int b = b0+bi;
        joint[(size_t)b*HH + n] = fmaxf(acc[bi] + b_pred[n] + b_enc[n], 0.0f);
    }
    if (tile == 0) slot[threadIdx.x] = 0ULL;
}

__global__ __launch_bounds__(256) void k_p3o(
    const float* __restrict__ Wout, const float* __restrict__ b_out,
    const float* __restrict__ joint, unsigned long long* __restrict__ slot)
{
    int tile = (blockIdx.x & 7)*34 + (blockIdx.x >> 3);
    int vt = tile >> 4, bg = tile & 15;
    int lane = threadIdx.x & 63, w = threadIdx.x >> 6;
    int v = vt*256 + w*64 + lane;
    bool valid = v < VV;
    int vv = valid ? v : (VV-1);
    int b0 = bg*8;
    float acc[8];
    #pragma unroll
    for (int i=0;i<8;i++) acc[i]=0.f;
    const float* wr = Wout + (size_t)vv*HH;
    for (int kc=0; kc<HH; kc+=16){
        float wv[16];
        #pragma unroll
        for (int q=0;q<4;q++){
            float4 f = *reinterpret_cast<const float4*>(wr + kc + q*4);
            wv[q*4+0]=f.x; wv[q*4+1]=f.y; wv[q*4+2]=f.z; wv[q*4+3]=f.w;
        }
        #pragma unroll
        for (int bi=0; bi<8; ++bi){
            int b = b0+bi;
            const float* jp = joint + (size_t)b*HH + kc;
            float a = acc[bi];
            #pragma unroll
            for (int k=0;k<16;k++) a = fmaf(jp[k], wv[k], a);
            acc[bi] = a;
        }
    }
    float bofl = b_out[vv];
    __shared__ unsigned long long redo[4][8];
    #pragma unroll
    for (int bi=0; bi<8; ++bi){
        unsigned long long key = valid ? packkey(acc[bi] + bofl, (unsigned)v) : 0ULL;
        #pragma unroll
        for (int off=32; off>0; off>>=1){
            unsigned long long o = __shfl_xor(key, off, 64);
            if (o > key) key = o;
        }
        if (lane == 0) redo[w][bi] = key;
    }
    __syncthreads();
    if (threadIdx.x < 8){
        int bi = threadIdx.x;
        unsigned long long m = redo[0][bi];
        #pragma unroll
        for (int q=1;q<4;q++) if (redo[q][bi] > m) m = redo[q][bi];
        atomicMax(&slot[b0+bi], m);
    }
}

__global__ __launch_bounds__(256) void k_finalo(const int* __restrict__ lens,
                        const unsigned long long* __restrict__ slot,
                        const float* __restrict__ hs_r, const float* __restrict__ h1_r,
                        const float* __restrict__ cso,  const float* __restrict__ c1o,
                        float* __restrict__ dout)
{
    int i = blockIdx.x*256 + threadIdx.x;
    if (i >= BB*HH) return;
    int b = i / HH;
    unsigned long long key = slot[b];
    int k = (int)(~(unsigned)key);
    bool m = ((TT-1) >= lens[b]) || (k == 0);
    dout[BB*TT + i]         = m ? hs_r[i] : h1_r[i];
    dout[BB*TT + BB*HH + i] = m ? cso[i]  : c1o[i];
    if (i < BB){
        unsigned long long key2 = slot[i];
        int k2 = (int)(~(unsigned)key2);
        bool mm = ((TT-1) >= lens[i]) || (k2 == 0);
        dout[(size_t)i*TT + (TT-1)] = mm ? 0.0f : (float)k2;
    }
}

extern "C" void kernel_launch(void* const* d_in, const int* in_sizes, int n_in,
                              void* d_out, int out_size, void* d_ws, size_t ws_size,
                              hipStream_t stream)
{
    const float* x     = (const float*)d_in[0];
    const int*   lens  = (const int*)  d_in[1];
    const float* emb   = (const float*)d_in[2];
    const float* Wih   = (const float*)d_in[3];
    const float* Whh   = (const float*)d_in[4];
    const float* bih   = (const float*)d_in[5];
    const float* bhh   = (const float*)d_in[6];
    const float* Wenc  = (const float*)d_in[7];
    const float* benc  = (const float*)d_in[8];
    const float* Wpred = (const float*)d_in[9];
    const float* bpred = (const float*)d_in[10];
    const float* Wout  = (const float*)d_in[11];
    const float* bout  = (const float*)d_in[12];
    const float* h0    = (const float*)d_in[13];
    const float* c0    = (const float*)d_in[14];
    float* out = (float*)d_out;
    (void)in_sizes; (void)n_in; (void)out_size;

    char* ws = (char*)d_ws;
    size_t off = 0;
    auto alloc = [&](size_t bytes) -> void* {
        void* p = ws + off; off += (bytes + 255) & ~(size_t)255; return p;
    };
    const size_t BH = (size_t)BB*HH*sizeof(float);
    float* hs0  = (float*)alloc(BH);
    float* hs1  = (float*)alloc(BH);
    float* h1b0 = (float*)alloc(BH);
    float* h1b1 = (float*)alloc(BH);
    float* cs   = (float*)alloc(BH);
    float* c1   = (float*)alloc(BH);
    float* joint= (float*)alloc(BH);
    int* label  = (int*)alloc(BB*sizeof(int));
    unsigned long long* slot8 = (unsigned long long*)alloc(8*BB*sizeof(unsigned long long));
    float* boutP = (float*)alloc((size_t)VP3*sizeof(float));
    float* WencT = (float*)alloc((size_t)HH*HH*sizeof(float));
    float* WhhP  = (float*)alloc((size_t)160*HH*16*sizeof(float));   // 6.55MB
    float* WpredP= (float*)alloc((size_t)160*HH*4*sizeof(float));    // 1.64MB
    float* WoutP = (float*)alloc((size_t)272*HH*16*sizeof(float));   // 11.14MB
    float* embproj  = (float*)alloc((size_t)(VV+1)*G4*sizeof(float));
    float* encprojT = (float*)alloc((size_t)TT*BB*HH*sizeof(float));
    size_t need = off;

    if (ws_size >= need){
        // temps aliased into encprojT region (consumed before k_encprojT2 writes it)
        char* A = (char*)encprojT;
        float* WhhT   = (float*)(A);               // 6.55MB
        float* WoutTr = (float*)(A + 7340032);     // 11.14MB
        float* WihT   = (float*)(A + 19922944);    // 6.55MB
        float* WpredT = (float*)(A + 27262976);    // 1.64MB

        k_init3<<<(BB*HH+255)/256, 256, 0, stream>>>(h0, c0, hs0, cs, label, slot8);
        k_tr_gate<<<(G4*160+255)/256, 256, 0, stream>>>(Whh, WhhT);
        k_packA<<<(160*HH*4+255)/256, 256, 0, stream>>>(WhhT, WhhP);
        k_tr640<<<(HH*160+255)/256, 256, 0, stream>>>(Wpred, WpredT);
        k_packB<<<(160*HH+255)/256, 256, 0, stream>>>(WpredT, WpredP);
        k_tr_woutr<<<(VP3*160+255)/256, 256, 0, stream>>>(Wout, WoutTr);
        k_packC<<<(272*HH*4+255)/256, 256, 0, stream>>>(WoutTr, WoutP);
        k_boutp<<<(VP3+255)/256, 256, 0, stream>>>(bout, boutP);
        k_tr_gate<<<(G4*160+255)/256, 256, 0, stream>>>(Wih, WihT);
        k_embproj2<<<17*160, 256, 0, stream>>>(emb, WihT, bih, bhh, embproj);
        k_tr640<<<(HH*160+255)/256, 256, 0, stream>>>(Wenc, WencT);
        k_encprojT2<<<20480, 128, 0, stream>>>(x, WencT, benc, encprojT);  // overwrites temps

        float* hsbuf[2] = {hs0, hs1};
        float* h1buf[2] = {h1b0, h1b1};
        for (int t = 0; t < TT; ++t){
            const float* hsr = hsbuf[t & 1];
            float*       hsw = hsbuf[(t+1) & 1];
            const float* h1r = h1buf[(t+1) & 1];
            float*       h1w = h1buf[t & 1];
            kA<<<160, 512, 0, stream>>>(WhhP, embproj, lens, hsr, hsw, h1r, h1w,
                                        cs, c1, label, slot8, out, t);
            kB<<<160, 512, 0, stream>>>(WpredP, encprojT, bpred, h1w, joint, slot8, t);
            kC<<<272, 512, 0, stream>>>(WoutP, boutP, joint, slot8);
        }
        kFin<<<(BB*HH+255)/256, 256, 0, stream>>>(lens, slot8, hsbuf[0], h1buf[1], cs, c1, out);
        return;
    }

    // -------- fallback: basic per-step path (small ws) --------
    {
        size_t foff = 0;
        auto falloc = [&](size_t bytes) -> void* {
            void* p = ws + foff; foff += (bytes + 255) & ~(size_t)255; return p;
        };
        float* fhs0  = (float*)falloc(BH);
        float* fhs1  = (float*)falloc(BH);
        float* fh1b0 = (float*)falloc(BH);
        float* fh1b1 = (float*)falloc(BH);
        float* fcs   = (float*)falloc(BH);
        float* fc1   = (float*)falloc(BH);
        float* fjoint= (float*)falloc(BH);
        int* flabel  = (int*)falloc(BB*sizeof(int));
        unsigned long long* fslot = (unsigned long long*)falloc(BB*sizeof(unsigned long long));

        k_init<<<(BB*HH+255)/256, 256, 0, stream>>>(h0, c0, fhs0, fcs, flabel, fslot);
        float* hsbuf[2] = {fhs0, fhs1};
        float* h1buf[2] = {fh1b0, fh1b1};
        for (int t = 0; t < TT; ++t){
            const float* hsr = hsbuf[t & 1];
            float*       hsw = hsbuf[(t+1) & 1];
            const float* h1r = h1buf[(t+1) & 1];
            float*       h1w = h1buf[t & 1];
            k_p1o<<<160, 256, 0, stream>>>(Whh, Wih, emb, bih, bhh, lens,
                                           hsr, hsw, h1r, h1w, fcs, fc1, flabel, fslot, out, t);
            k_p2o<<<160, 128, 0, stream>>>(Wpred, Wenc, x, benc, bpred, h1w, fjoint, fslot, t);
            k_p3o<<<272, 256, 0, stream>>>(Wout, bout, fjoint, fslot);
        }
        k_finalo<<<(BB*HH+255)/256, 256, 0, stream>>>(lens, fslot, hsbuf[0], h1buf[1], fcs, fc1, out);
    }
}

// Round 12
// 29059.296 us; speedup vs baseline: 4.0141x; 1.0356x over previous
//
#include <hip/hip_runtime.h>
#include <stdint.h>

#define HH 640
#define BB 128
#define TT 512
#define VV 4097
#define G4 2560
#define VP3 4352   // 256*17 padded vocab

typedef float f32x4v __attribute__((ext_vector_type(4)));

__device__ __forceinline__ float sigm(float x){ return 1.0f/(1.0f+expf(-x)); }

// monotonic packed key: larger logit wins; ties -> smaller v (jnp.argmax first-index)
__device__ __forceinline__ unsigned long long packkey(float f, unsigned v){
    unsigned u = __float_as_uint(f);
    unsigned m = (u & 0x80000000u) ? ~u : (u | 0x80000000u);
    return ((unsigned long long)m << 32) | (unsigned long long)(~v);
}
__device__ __forceinline__ int xcd_tile(int bid, int per){ return (bid & 7)*per + (bid >> 3); }
// transposed state addressing: [k>>2][b][k&3]
__device__ __forceinline__ size_t taddr(int k, int b){
    return ((size_t)(k>>2)*BB + b)*4 + (k&3);
}

// ---------------- init (transposed state) ----------------
__global__ __launch_bounds__(256) void k_init3(const float* __restrict__ h0, const float* __restrict__ c0,
                       float* __restrict__ hs0, float* __restrict__ csT,
                       int* __restrict__ label, unsigned long long* __restrict__ slot8){
    int i = blockIdx.x*256 + threadIdx.x;
    if (i < BB*HH){
        int b = i / HH, jj = i % HH;
        size_t o = taddr(jj, b);
        hs0[o] = h0[i]; csT[o] = c0[i];
    }
    if (i < BB) label[i] = 0;
    if (i < 8*BB) slot8[i] = 0ULL;
}

// ---------------- one-time transposes ----------------
__global__ __launch_bounds__(256) void k_tr_gate(const float* __restrict__ W, float* __restrict__ WT){
    int idx = blockIdx.x*256 + threadIdx.x;
    if (idx >= G4*160) return;
    int row = idx / 160, kq = idx % 160;
    int g = row / HH, jj = row % HH;
    float4 f = *reinterpret_cast<const float4*>(W + (size_t)row*HH + kq*4);
    WT[(size_t)(kq*4+0)*G4 + jj*4+g] = f.x;
    WT[(size_t)(kq*4+1)*G4 + jj*4+g] = f.y;
    WT[(size_t)(kq*4+2)*G4 + jj*4+g] = f.z;
    WT[(size_t)(kq*4+3)*G4 + jj*4+g] = f.w;
}
__global__ __launch_bounds__(256) void k_tr640(const float* __restrict__ W, float* __restrict__ WT){
    int idx = blockIdx.x*256 + threadIdx.x;
    if (idx >= HH*160) return;
    int n = idx / 160, kq = idx % 160;
    float4 f = *reinterpret_cast<const float4*>(W + (size_t)n*HH + kq*4);
    WT[(size_t)(kq*4+0)*HH + n] = f.x;
    WT[(size_t)(kq*4+1)*HH + n] = f.y;
    WT[(size_t)(kq*4+2)*HH + n] = f.z;
    WT[(size_t)(kq*4+3)*HH + n] = f.w;
}
__global__ __launch_bounds__(256) void k_tr_woutr(const float* __restrict__ W, float* __restrict__ WT){
    int idx = blockIdx.x*256 + threadIdx.x;
    if (idx >= VP3*160) return;
    int v = idx / 160, kq = idx % 160;
    float4 f = make_float4(0.f,0.f,0.f,0.f);
    if (v < VV) f = *reinterpret_cast<const float4*>(W + (size_t)v*HH + kq*4);
    WT[(size_t)(kq*4+0)*VP3 + v] = f.x;
    WT[(size_t)(kq*4+1)*VP3 + v] = f.y;
    WT[(size_t)(kq*4+2)*VP3 + v] = f.z;
    WT[(size_t)(kq*4+3)*VP3 + v] = f.w;
}
__global__ __launch_bounds__(256) void k_boutp(const float* __restrict__ b_out, float* __restrict__ bp){
    int v = blockIdx.x*256 + threadIdx.x;
    if (v < VP3) bp[v] = (v < VV) ? b_out[v] : -1e30f;
}

// ---------------- per-block contiguous weight packs ----------------
// WhhP[bid][k][16] <- WhhT[k*G4 + bid*16 + ...]
__global__ __launch_bounds__(256) void k_packA(const float* __restrict__ WhhT, float* __restrict__ WhhP){
    int i = blockIdx.x*256 + threadIdx.x;      // granules: 160*640*4
    if (i >= 160*HH*4) return;
    int bid = i / (HH*4), rem = i % (HH*4);
    int k = rem >> 2, q = rem & 3;
    reinterpret_cast<float4*>(WhhP)[i] =
        *reinterpret_cast<const float4*>(&WhhT[(size_t)k*G4 + bid*16 + q*4]);
}
// WpredP[bid][k][4]
__global__ __launch_bounds__(256) void k_packB(const float* __restrict__ WpredT, float* __restrict__ WpredP){
    int i = blockIdx.x*256 + threadIdx.x;      // granules: 160*640
    if (i >= 160*HH) return;
    int bid = i / HH, k = i % HH;
    reinterpret_cast<float4*>(WpredP)[i] =
        *reinterpret_cast<const float4*>(&WpredT[(size_t)k*HH + bid*4]);
}
// WoutP2[bid][k][20]: cols bid*17 .. bid*17+16, 3 zero pad (guarded scalar reads)
__global__ __launch_bounds__(256) void k_packC2(const float* __restrict__ WoutTr, float* __restrict__ WoutP){
    int i = blockIdx.x*256 + threadIdx.x;      // granules: 256*640*5
    if (i >= 256*HH*5) return;
    int bid = i / (HH*5), rem = i % (HH*5);
    int k = rem / 5, q = rem % 5;
    float4 f;
    #pragma unroll
    for (int e=0;e<4;++e){
        int u = q*4 + e;
        int col = bid*17 + u;
        float vv = (u < 17 && col < VP3) ? WoutTr[(size_t)k*VP3 + col] : 0.f;
        (&f.x)[e] = vv;
    }
    reinterpret_cast<float4*>(WoutP)[i] = f;
}

// ---------------- emb_proj: [VV+1][2560] gate-interleaved; row VV = bias-only ----------------
__global__ __launch_bounds__(256) void k_embproj2(const float* __restrict__ emb,
                          const float* __restrict__ WihT,
                          const float* __restrict__ b_ih, const float* __restrict__ b_hh,
                          float* __restrict__ embproj){
    __shared__ float lw[640*16];
    int vt = blockIdx.x / 160, ut = blockIdx.x % 160;
    for (int i=threadIdx.x; i<640*16; i+=256)
        lw[i] = WihT[(size_t)(i>>4)*G4 + ut*16 + (i&15)];
    float bias[16];
    #pragma unroll
    for (int u=0;u<16;++u){
        int gu = ut*16+u, jj = gu>>2, g = gu&3;
        bias[u] = b_ih[g*HH+jj] + b_hh[g*HH+jj];
    }
    __syncthreads();
    int v = vt*256 + threadIdx.x;
    float acc[16];
    #pragma unroll
    for (int u=0;u<16;++u) acc[u]=0.f;
    if (v < VV){
        const float4* er = reinterpret_cast<const float4*>(emb + (size_t)v*HH);
        for (int k4=0;k4<160;++k4){
            float4 ev = er[k4];
            #pragma unroll
            for (int q=0;q<4;++q){
                float e = (q==0)?ev.x:(q==1)?ev.y:(q==2)?ev.z:ev.w;
                const f32x4v* wr = reinterpret_cast<const f32x4v*>(&lw[(k4*4+q)*16]);
                #pragma unroll
                for (int g=0; g<4; ++g){
                    f32x4v w = wr[g];
                    #pragma unroll
                    for (int ee=0; ee<4; ++ee) acc[g*4+ee] = fmaf(w[ee], e, acc[g*4+ee]);
                }
            }
        }
    }
    if (v <= VV){
        #pragma unroll
        for (int q=0;q<4;++q){
            float4 st = make_float4(acc[q*4+0]+bias[q*4+0], acc[q*4+1]+bias[q*4+1],
                                    acc[q*4+2]+bias[q*4+2], acc[q*4+3]+bias[q*4+3]);
            *reinterpret_cast<float4*>(embproj + (size_t)v*G4 + ut*16 + q*4) = st;
        }
    }
}

// ---------------- enc_proj precompute, layout [t][n][b] ----------------
__global__ __launch_bounds__(128) void k_encprojT2(const float* __restrict__ x,
                          const float* __restrict__ WencT, const float* __restrict__ b_enc,
                          float* __restrict__ encprojT){
    int tile = (blockIdx.x & 7)*2560 + (blockIdx.x >> 3);
    int b   = tile / 160;
    int rem = tile % 160;
    int tt  = rem / 5;
    int nt2 = rem % 5;
    int n = nt2*128 + threadIdx.x;
    float acc[16];
    #pragma unroll
    for (int i=0;i<16;i++) acc[i]=0.f;
    const float* xb = x + (size_t)b*HH*TT + tt*16;
    #pragma unroll 4
    for (int k=0;k<HH;++k){
        float wv = WencT[(size_t)k*HH + n];
        const float4* xp = reinterpret_cast<const float4*>(xb + (size_t)k*TT);
        float4 x0=xp[0], x1=xp[1], x2=xp[2], x3=xp[3];
        acc[0]=fmaf(x0.x,wv,acc[0]);  acc[1]=fmaf(x0.y,wv,acc[1]);
        acc[2]=fmaf(x0.z,wv,acc[2]);  acc[3]=fmaf(x0.w,wv,acc[3]);
        acc[4]=fmaf(x1.x,wv,acc[4]);  acc[5]=fmaf(x1.y,wv,acc[5]);
        acc[6]=fmaf(x1.z,wv,acc[6]);  acc[7]=fmaf(x1.w,wv,acc[7]);
        acc[8]=fmaf(x2.x,wv,acc[8]);  acc[9]=fmaf(x2.y,wv,acc[9]);
        acc[10]=fmaf(x2.z,wv,acc[10]); acc[11]=fmaf(x2.w,wv,acc[11]);
        acc[12]=fmaf(x3.x,wv,acc[12]); acc[13]=fmaf(x3.y,wv,acc[13]);
        acc[14]=fmaf(x3.z,wv,acc[14]); acc[15]=fmaf(x3.w,wv,acc[15]);
    }
    float be = b_enc[n];
    #pragma unroll
    for (int ti=0; ti<16; ++ti)
        encprojT[((size_t)(tt*16+ti)*HH + n)*BB + b] = acc[ti] + be;
}

// ================= per-step kernels =================

// ---- A: gates GEMM + LSTM nonlin + lazy commit of t-1 ----
__global__ __launch_bounds__(512) void kA(
    const float* __restrict__ WhhP, const float* __restrict__ embproj,
    const int* __restrict__ lens,
    const float* __restrict__ hsrT, float* __restrict__ hswT,
    const float* __restrict__ h1rT, float* __restrict__ h1wT,
    float* __restrict__ csT, float* __restrict__ c1T,
    int* __restrict__ label, const unsigned long long* __restrict__ slot8,
    float* __restrict__ out_emit, int t)
{
    __shared__ float lw[HH*16];        // 41 KB
    __shared__ float red[3*16*128];    // 24.6 KB
    const int bid = xcd_tile(blockIdx.x, 20);   // 160 blocks, 16 gate-units each
    const int tid = threadIdx.x;
    const int b = tid & 127, kh = tid >> 7;
    const int u0 = bid*16;

    {
        const float4* wsrc = reinterpret_cast<const float4*>(WhhP + (size_t)bid*(HH*16));
        float4* ld = reinterpret_cast<float4*>(lw);
        for (int i=tid; i<HH*4; i+=512) ld[i] = wsrc[i];
    }

    bool mask; int sel=0, kprev=0;
    if (t==0){ mask=true; sel=0; }
    else{
        unsigned long long key = slot8[b];
        #pragma unroll
        for (int q=1;q<8;++q){ unsigned long long o=slot8[q*128+b]; if(o>key)key=o; }
        int k = (int)(~(unsigned)key);
        int lab = label[b];
        mask = ((t-1) >= lens[b]) || (k==0);
        kprev = k; sel = mask ? lab : k;
    }
    __syncthreads();

    const float4* hp = reinterpret_cast<const float4*>(mask ? hsrT : h1rT);
    float a1[16];
    #pragma unroll
    for (int u=0;u<16;++u) a1[u]=0.f;
    const int k0 = kh*40;
    #pragma unroll 4
    for (int k4=k0; k4<k0+40; ++k4){
        float4 hv = hp[(size_t)k4*BB + b];
        #pragma unroll
        for (int q=0;q<4;++q){
            float h = (q==0)?hv.x:(q==1)?hv.y:(q==2)?hv.z:hv.w;
            const f32x4v* wr = reinterpret_cast<const f32x4v*>(&lw[(k4*4+q)*16]);
            #pragma unroll
            for (int g=0; g<4; ++g){
                f32x4v w = wr[g];
                #pragma unroll
                for (int ee=0; ee<4; ++ee) a1[g*4+ee] = fmaf(w[ee], h, a1[g*4+ee]);
            }
        }
    }
    if (kh > 0){
        #pragma unroll
        for (int u=0;u<16;++u) red[((kh-1)*16+u)*128 + b] = a1[u];
    }
    __syncthreads();
    if (kh == 0){
        int erow = (t==0) ? VV : sel;
        const float4* eb = reinterpret_cast<const float4*>(embproj + (size_t)erow*G4 + u0);
        const size_t g4 = (size_t)bid*BB + b;   // float4 granule (units bid*4..+3)
        float4 ce4 = mask ? reinterpret_cast<const float4*>(csT)[g4]
                          : reinterpret_cast<const float4*>(c1T)[g4];
        float4 he4 = mask ? reinterpret_cast<const float4*>(hsrT)[g4]
                          : reinterpret_cast<const float4*>(h1rT)[g4];
        float cn[4], hn[4];
        const float* cep = &ce4.x;
        #pragma unroll
        for (int jl=0; jl<4; ++jl){
            float4 e = eb[jl];
            float gi = a1[jl*4+0] + red[(jl*4+0)*128+b] + red[(16+jl*4+0)*128+b] + red[(32+jl*4+0)*128+b] + e.x;
            float gf = a1[jl*4+1] + red[(jl*4+1)*128+b] + red[(16+jl*4+1)*128+b] + red[(32+jl*4+1)*128+b] + e.y;
            float gg = a1[jl*4+2] + red[(jl*4+2)*128+b] + red[(16+jl*4+2)*128+b] + red[(32+jl*4+2)*128+b] + e.z;
            float go = a1[jl*4+3] + red[(jl*4+3)*128+b] + red[(16+jl*4+3)*128+b] + red[(32+jl*4+3)*128+b] + e.w;
            float ce = cep[jl];
            float cv = sigm(gf)*ce + sigm(gi)*tanhf(gg);
            cn[jl] = cv;
            hn[jl] = sigm(go)*tanhf(cv);
        }
        reinterpret_cast<float4*>(csT)[g4]  = ce4;                                  // committed thru t-1
        reinterpret_cast<float4*>(c1T)[g4]  = make_float4(cn[0],cn[1],cn[2],cn[3]); // tentative t
        reinterpret_cast<float4*>(hswT)[g4] = he4;
        reinterpret_cast<float4*>(h1wT)[g4] = make_float4(hn[0],hn[1],hn[2],hn[3]);
        if (bid == 0){
            if (t > 0) out_emit[(size_t)b*TT + (t-1)] = mask ? 0.f : (float)kprev;
            label[b] = sel;   // idempotent-select race-safe
        }
    }
}

// ---- B: joint = relu(h1@WpredT + b_pred + encprojT[t]) ; reset slots ----
__global__ __launch_bounds__(512) void kB(
    const float* __restrict__ WpredP, const float* __restrict__ encprojT,
    const float* __restrict__ b_pred, const float* __restrict__ h1T,
    float* __restrict__ jointT, unsigned long long* __restrict__ slot8, int t)
{
    __shared__ float lw[HH*4];        // 10.2 KB
    __shared__ float red[3*4*128];    // 6.1 KB
    const int bid = xcd_tile(blockIdx.x, 20);   // 160 blocks, 4 n each
    const int tid = threadIdx.x;
    const int b = tid & 127, kh = tid >> 7;
    const int n0 = bid*4;
    {
        const float4* wsrc = reinterpret_cast<const float4*>(WpredP + (size_t)bid*(HH*4));
        float4* ld = reinterpret_cast<float4*>(lw);
        for (int i=tid; i<HH; i+=512) ld[i] = wsrc[i];
    }
    if (bid == 0 && kh == 3){   // reset slots (A consumed them; C refills)
        #pragma unroll
        for (int q=0;q<8;++q) slot8[q*128 + b] = 0ULL;
    }
    __syncthreads();
    const float4* hp = reinterpret_cast<const float4*>(h1T);
    float a[4] = {0.f,0.f,0.f,0.f};
    const int k0 = kh*40;
    #pragma unroll 4
    for (int k4=k0; k4<k0+40; ++k4){
        float4 hv = hp[(size_t)k4*BB + b];
        #pragma unroll
        for (int q=0;q<4;++q){
            float h = (q==0)?hv.x:(q==1)?hv.y:(q==2)?hv.z:hv.w;
            f32x4v w = *reinterpret_cast<const f32x4v*>(&lw[(k4*4+q)*4]);
            #pragma unroll
            for (int ee=0; ee<4; ++ee) a[ee] = fmaf(w[ee], h, a[ee]);
        }
    }
    if (kh > 0){
        #pragma unroll
        for (int u=0;u<4;++u) red[((kh-1)*4+u)*128 + b] = a[u];
    }
    __syncthreads();
    if (kh == 0){
        float jn[4];
        #pragma unroll
        for (int u=0;u<4;++u){
            float s = a[u] + red[u*128+b] + red[(4+u)*128+b] + red[(8+u)*128+b]
                    + b_pred[n0+u] + encprojT[((size_t)t*HH + n0+u)*BB + b];
            jn[u] = fmaxf(s, 0.f);
        }
        reinterpret_cast<float4*>(jointT)[(size_t)bid*BB + b] =
            make_float4(jn[0],jn[1],jn[2],jn[3]);
    }
}

// ---- C: logits + argmax (256 blocks x 17 v) ----
__global__ __launch_bounds__(512) void kC(
    const float* __restrict__ WoutP, const float* __restrict__ boutP,
    const float* __restrict__ jointT, unsigned long long* __restrict__ slot8)
{
    __shared__ float lw[HH*20];        // 51.2 KB (17 used)
    __shared__ float red[3*17*128];    // 26.1 KB
    const int bid = xcd_tile(blockIdx.x, 32);   // 256 blocks, 17 v each
    const int tid = threadIdx.x;
    const int b = tid & 127, kh = tid >> 7;
    const int v0 = bid*17;
    {
        const float4* wsrc = reinterpret_cast<const float4*>(WoutP + (size_t)bid*(HH*20));
        float4* ld = reinterpret_cast<float4*>(lw);
        for (int i=tid; i<HH*5; i+=512) ld[i] = wsrc[i];
    }
    __syncthreads();
    const float4* jp = reinterpret_cast<const float4*>(jointT);
    float a[17];
    #pragma unroll
    for (int u=0;u<17;++u) a[u]=0.f;
    const int k0 = kh*40;
    #pragma unroll 4
    for (int k4=k0; k4<k0+40; ++k4){
        float4 jv = jp[(size_t)k4*BB + b];
        #pragma unroll
        for (int q=0;q<4;++q){
            float h = (q==0)?jv.x:(q==1)?jv.y:(q==2)?jv.z:jv.w;
            const float* base = &lw[(k4*4+q)*20];
            const f32x4v* wr = reinterpret_cast<const f32x4v*>(base);
            #pragma unroll
            for (int g=0; g<4; ++g){
                f32x4v w = wr[g];
                #pragma unroll
                for (int ee=0; ee<4; ++ee) a[g*4+ee] = fmaf(w[ee], h, a[g*4+ee]);
            }
            a[16] = fmaf(base[16], h, a[16]);
        }
    }
    if (kh > 0){
        #pragma unroll
        for (int u=0;u<17;++u) red[((kh-1)*17+u)*128 + b] = a[u];
    }
    __syncthreads();
    if (kh == 0){
        unsigned long long key = 0ULL;
        #pragma unroll
        for (int u=0;u<17;++u){
            float s = a[u] + red[u*128+b] + red[(17+u)*128+b] + red[(34+u)*128+b] + boutP[v0+u];
            unsigned long long kk = packkey(s, (unsigned)(v0+u));
            if (kk > key) key = kk;
        }
        atomicMax(&slot8[(bid&7)*128 + b], key);
    }
}

// ---- final: emit t=511, hF, cF ----
__global__ __launch_bounds__(256) void kFin(const int* __restrict__ lens,
                        const unsigned long long* __restrict__ slot8,
                        const float* __restrict__ hsT, const float* __restrict__ h1T,
                        const float* __restrict__ csT, const float* __restrict__ c1T,
                        float* __restrict__ dout)
{
    int i = blockIdx.x*256 + threadIdx.x;
    if (i >= BB*HH) return;
    int b = i / HH, jj = i % HH;
    unsigned long long key = slot8[b];
    #pragma unroll
    for (int q=1;q<8;++q){ unsigned long long o=slot8[q*128+b]; if(o>key)key=o; }
    int k = (int)(~(unsigned)key);
    bool m = ((TT-1) >= lens[b]) || (k == 0);
    size_t o = taddr(jj, b);
    dout[BB*TT + i]         = m ? hsT[o] : h1T[o];
    dout[BB*TT + BB*HH + i] = m ? csT[o] : c1T[o];
    if (i < BB){
        unsigned long long key2 = slot8[i];
        #pragma unroll
        for (int q=1;q<8;++q){ unsigned long long o2=slot8[q*128+i]; if(o2>key2)key2=o2; }
        int k2 = (int)(~(unsigned)key2);
        bool mm = ((TT-1) >= lens[i]) || (k2 == 0);
        dout[(size_t)i*TT + (TT-1)] = mm ? 0.0f : (float)k2;
    }
}

// ================= fallback (small ws): basic per-step kernels =================
__global__ __launch_bounds__(256) void k_init(const float* __restrict__ h0, const float* __restrict__ c0,
                       float* __restrict__ hs0, float* __restrict__ cso,
                       int* __restrict__ label, unsigned long long* __restrict__ slot){
    int i = blockIdx.x*256 + threadIdx.x;
    if (i < BB*HH){ hs0[i] = h0[i]; cso[i] = c0[i]; }
    if (i < BB){ label[i] = 0; slot[i] = 0ULL; }
}

__global__ __launch_bounds__(256) void k_p1o(
    const float* __restrict__ Whh, const float* __restrict__ Wih,
    const float* __restrict__ embedding,
    const float* __restrict__ b_ih, const float* __restrict__ b_hh,
    const int* __restrict__ lens,
    const float* __restrict__ hs_r, float* __restrict__ hs_w,
    const float* __restrict__ h1_r, float* __restrict__ h1_w,
    float* c_state, float* c1o, int* label,
    const unsigned long long* __restrict__ slot,
    float* __restrict__ out_emit, int t)
{
    int tile = (blockIdx.x & 7)*20 + (blockIdx.x >> 3);
    int jt = tile >> 4, bg = tile & 15;
    int lane = threadIdx.x & 63, w = threadIdx.x >> 6;
    int j = (jt<<6) + lane, b0 = bg<<3;

    bool mask[8]; int kprev[8]; int sel[8];
    #pragma unroll
    for (int bi=0; bi<8; ++bi){
        int b = b0+bi;
        if (t == 0){ mask[bi]=true; sel[bi]=0; kprev[bi]=0; }
        else {
            unsigned long long key = slot[b];
            int k = (int)(~(unsigned)key);
            int lab = label[b];
            bool m = ((t-1) >= lens[b]) || (k == 0);
            mask[bi]=m; kprev[bi]=k; sel[bi] = m ? lab : k;
        }
    }
    float acc[8];
    #pragma unroll
    for (int i=0;i<8;i++) acc[i]=0.f;
    const float* wrow  = Whh + (size_t)(w*HH + j)*HH;
    const float* wrow2 = Wih + (size_t)(w*HH + j)*HH;
    for (int kc=0; kc<HH; kc+=16){
        float wv[16], wv2[16];
        #pragma unroll
        for (int q=0;q<4;q++){
            float4 f = *reinterpret_cast<const float4*>(wrow + kc + q*4);
            wv[q*4+0]=f.x; wv[q*4+1]=f.y; wv[q*4+2]=f.z; wv[q*4+3]=f.w;
            float4 f2 = *reinterpret_cast<const float4*>(wrow2 + kc + q*4);
            wv2[q*4+0]=f2.x; wv2[q*4+1]=f2.y; wv2[q*4+2]=f2.z; wv2[q*4+3]=f2.w;
        }
        #pragma unroll
        for (int bi=0; bi<8; ++bi){
            int b = b0+bi;
            const float* hp0 = hs_r + (size_t)b*HH + kc;
            const float* hp1 = h1_r + (size_t)b*HH + kc;
            float a = acc[bi];
            if (mask[bi]){
                #pragma unroll
                for (int k=0;k<16;k++) a = fmaf(hp0[k], wv[k], a);
            } else {
                #pragma unroll
                for (int k=0;k<16;k++) a = fmaf(hp1[k], wv[k], a);
            }
            if (t > 0){
                const float* ep = embedding + (size_t)sel[bi]*HH + kc;
                #pragma unroll
                for (int k=0;k<16;k++) a = fmaf(ep[k], wv2[k], a);
            }
            acc[bi] = a;
        }
    }
    __shared__ float xch[8][4][64];
    #pragma unroll
    for (int bi=0; bi<8; ++bi)
        xch[bi][w][lane] = acc[bi] + b_ih[w*HH + j] + b_hh[w*HH + j];
    __syncthreads();
    #pragma unroll
    for (int rr=0; rr<2; ++rr){
        int bi = (w<<1) + rr;
        int b  = b0 + bi;
        size_t o = (size_t)b*HH + j;
        float gi = xch[bi][0][lane], gf = xch[bi][1][lane];
        float gg = xch[bi][2][lane], go = xch[bi][3][lane];
        float ce = mask[bi] ? c_state[o] : c1o[o];
        float c2 = sigm(gf)*ce + sigm(gi)*tanhf(gg);
        float h2 = sigm(go)*tanhf(c2);
        float he = mask[bi] ? hs_r[o] : h1_r[o];
        c_state[o] = ce; c1o[o] = c2; hs_w[o] = he; h1_w[o] = h2;
    }
    if (jt == 0 && t > 0 && threadIdx.x < 8){
        int bi = threadIdx.x; int b = b0 + bi;
        out_emit[(size_t)b*TT + (t-1)] = mask[bi] ? 0.0f : (float)kprev[bi];
        label[b] = sel[bi];
    }
}

__global__ __launch_bounds__(128) void k_p2o(
    const float* __restrict__ Wpred, const float* __restrict__ Wenc,
    const float* __restrict__ x, const float* __restrict__ b_enc,
    const float* __restrict__ b_pred, const float* __restrict__ h1,
    float* __restrict__ joint, unsigned long long* __restrict__ slot, int t)
{
    int tile = (blockIdx.x & 7)*20 + (blockIdx.x >> 3);
    int nt = tile / 32, bg = tile % 32;
    int lane = threadIdx.x & 63, w = threadIdx.x >> 6;
    int n = nt*128 + w*64 + lane, b0 = bg*4;
    float acc[4] = {0.f,0.f,0.f,0.f};
    const float* wr  = Wpred + (size_t)n*HH;
    const float* wr2 = Wenc  + (size_t)n*HH;
    for (int kc=0; kc<HH; kc+=16){
        float wv[16], wv2[16];
        #pragma unroll
        for (int q=0;q<4;q++){
            float4 f = *reinterpret_cast<const float4*>(wr + kc + q*4);
            wv[q*4+0]=f.x; wv[q*4+1]=f.y; wv[q*4+2]=f.z; wv[q*4+3]=f.w;
            float4 f2 = *reinterpret_cast<const float4*>(wr2 + kc + q*4);
            wv2[q*4+0]=f2.x; wv2[q*4+1]=f2.y; wv2[q*4+2]=f2.z; wv2[q*4+3]=f2.w;
        }
        #pragma unroll
        for (int bi=0; bi<4; ++bi){
            int b = b0+bi;
            const float* hp = h1 + (size_t)b*HH + kc;
            float a = acc[bi];
            #pragma unroll
            for (int k=0;k<16;k++) a = fmaf(hp[k], wv[k], a);
            const float* xp = x + (size_t)b*HH*TT + (size_t)kc*TT + t;
            #pragma unroll
            for (int k=0;k<16;k++) a = fmaf(xp[(size_t)k*TT], wv2[k], a);
            acc[bi] = a;
        }
    }
    #pragma unroll
    for (int bi=0; bi<4; ++bi){
        int b = b0+bi;
        joint[(size_t)b*HH + n] = fmaxf(acc[bi] + b_pred[n] + b_enc[n], 0.0f);
    }
    if (tile == 0) slot[threadIdx.x] = 0ULL;
}

__global__ __launch_bounds__(256) void k_p3o(
    const float* __restrict__ Wout, const float* __restrict__ b_out,
    const float* __restrict__ joint, unsigned long long* __restrict__ slot)
{
    int tile = (blockIdx.x & 7)*34 + (blockIdx.x >> 3);
    int vt = tile >> 4, bg = tile & 15;
    int lane = threadIdx.x & 63, w = threadIdx.x >> 6;
    int v = vt*256 + w*64 + lane;
    bool valid = v < VV;
    int vv = valid ? v : (VV-1);
    int b0 = bg*8;
    float acc[8];
    #pragma unroll
    for (int i=0;i<8;i++) acc[i]=0.f;
    const float* wr = Wout + (size_t)vv*HH;
    for (int kc=0; kc<HH; kc+=16){
        float wv[16];
        #pragma unroll
        for (int q=0;q<4;q++){
            float4 f = *reinterpret_cast<const float4*>(wr + kc + q*4);
            wv[q*4+0]=f.x; wv[q*4+1]=f.y; wv[q*4+2]=f.z; wv[q*4+3]=f.w;
        }
        #pragma unroll
        for (int bi=0; bi<8; ++bi){
            int b = b0+bi;
            const float* jp = joint + (size_t)b*HH + kc;
            float a = acc[bi];
            #pragma unroll
            for (int k=0;k<16;k++) a = fmaf(jp[k], wv[k], a);
            acc[bi] = a;
        }
    }
    float bofl = b_out[vv];
    __shared__ unsigned long long redo[4][8];
    #pragma unroll
    for (int bi=0; bi<8; ++bi){
        unsigned long long key = valid ? packkey(acc[bi] + bofl, (unsigned)v) : 0ULL;
        #pragma unroll
        for (int off=32; off>0; off>>=1){
            unsigned long long o = __shfl_xor(key, off, 64);
            if (o > key) key = o;
        }
        if (lane == 0) redo[w][bi] = key;
    }
    __syncthreads();
    if (threadIdx.x < 8){
        int bi = threadIdx.x;
        unsigned long long m = redo[0][bi];
        #pragma unroll
        for (int q=1;q<4;q++) if (redo[q][bi] > m) m = redo[q][bi];
        atomicMax(&slot[b0+bi], m);
    }
}

__global__ __launch_bounds__(256) void k_finalo(const int* __restrict__ lens,
                        const unsigned long long* __restrict__ slot,
                        const float* __restrict__ hs_r, const float* __restrict__ h1_r,
                        const float* __restrict__ cso,  const float* __restrict__ c1o,
                        float* __restrict__ dout)
{
    int i = blockIdx.x*256 + threadIdx.x;
    if (i >= BB*HH) return;
    int b = i / HH;
    unsigned long long key = slot[b];
    int k = (int)(~(unsigned)key);
    bool m = ((TT-1) >= lens[b]) || (k == 0);
    dout[BB*TT + i]         = m ? hs_r[i] : h1_r[i];
    dout[BB*TT + BB*HH + i] = m ? cso[i]  : c1o[i];
    if (i < BB){
        unsigned long long key2 = slot[i];
        int k2 = (int)(~(unsigned)key2);
        bool mm = ((TT-1) >= lens[i]) || (k2 == 0);
        dout[(size_t)i*TT + (TT-1)] = mm ? 0.0f : (float)k2;
    }
}

extern "C" void kernel_launch(void* const* d_in, const int* in_sizes, int n_in,
                              void* d_out, int out_size, void* d_ws, size_t ws_size,
                              hipStream_t stream)
{
    const float* x     = (const float*)d_in[0];
    const int*   lens  = (const int*)  d_in[1];
    const float* emb   = (const float*)d_in[2];
    const float* Wih   = (const float*)d_in[3];
    const float* Whh   = (const float*)d_in[4];
    const float* bih   = (const float*)d_in[5];
    const float* bhh   = (const float*)d_in[6];
    const float* Wenc  = (const float*)d_in[7];
    const float* benc  = (const float*)d_in[8];
    const float* Wpred = (const float*)d_in[9];
    const float* bpred = (const float*)d_in[10];
    const float* Wout  = (const float*)d_in[11];
    const float* bout  = (const float*)d_in[12];
    const float* h0    = (const float*)d_in[13];
    const float* c0    = (const float*)d_in[14];
    float* out = (float*)d_out;
    (void)in_sizes; (void)n_in; (void)out_size;

    char* ws = (char*)d_ws;
    size_t off = 0;
    auto alloc = [&](size_t bytes) -> void* {
        void* p = ws + off; off += (bytes + 255) & ~(size_t)255; return p;
    };
    const size_t BH = (size_t)BB*HH*sizeof(float);
    float* hs0  = (float*)alloc(BH);
    float* hs1  = (float*)alloc(BH);
    float* h1b0 = (float*)alloc(BH);
    float* h1b1 = (float*)alloc(BH);
    float* cs   = (float*)alloc(BH);
    float* c1   = (float*)alloc(BH);
    float* joint= (float*)alloc(BH);
    int* label  = (int*)alloc(BB*sizeof(int));
    unsigned long long* slot8 = (unsigned long long*)alloc(8*BB*sizeof(unsigned long long));
    float* boutP = (float*)alloc((size_t)VP3*sizeof(float));
    float* WencT = (float*)alloc((size_t)HH*HH*sizeof(float));
    float* WhhP  = (float*)alloc((size_t)160*HH*16*sizeof(float));   // 6.55MB
    float* WpredP= (float*)alloc((size_t)160*HH*4*sizeof(float));    // 1.64MB
    float* WoutP = (float*)alloc((size_t)256*HH*20*sizeof(float));   // 13.1MB
    float* embproj  = (float*)alloc((size_t)(VV+1)*G4*sizeof(float));
    float* encprojT = (float*)alloc((size_t)TT*BB*HH*sizeof(float));
    size_t need = off;

    if (ws_size >= need){
        // temps aliased into encprojT region (consumed before k_encprojT2 writes it)
        char* A = (char*)encprojT;
        float* WhhT   = (float*)(A);               // 6.55MB
        float* WoutTr = (float*)(A + 7340032);     // 11.14MB
        float* WihT   = (float*)(A + 19922944);    // 6.55MB
        float* WpredT = (float*)(A + 27262976);    // 1.64MB

        k_init3<<<(BB*HH+255)/256, 256, 0, stream>>>(h0, c0, hs0, cs, label, slot8);
        k_tr_gate<<<(G4*160+255)/256, 256, 0, stream>>>(Whh, WhhT);
        k_packA<<<(160*HH*4+255)/256, 256, 0, stream>>>(WhhT, WhhP);
        k_tr640<<<(HH*160+255)/256, 256, 0, stream>>>(Wpred, WpredT);
        k_packB<<<(160*HH+255)/256, 256, 0, stream>>>(WpredT, WpredP);
        k_tr_woutr<<<(VP3*160+255)/256, 256, 0, stream>>>(Wout, WoutTr);
        k_packC2<<<(256*HH*5+255)/256, 256, 0, stream>>>(WoutTr, WoutP);
        k_boutp<<<(VP3+255)/256, 256, 0, stream>>>(bout, boutP);
        k_tr_gate<<<(G4*160+255)/256, 256, 0, stream>>>(Wih, WihT);
        k_embproj2<<<17*160, 256, 0, stream>>>(emb, WihT, bih, bhh, embproj);
        k_tr640<<<(HH*160+255)/256, 256, 0, stream>>>(Wenc, WencT);
        k_encprojT2<<<20480, 128, 0, stream>>>(x, WencT, benc, encprojT);  // overwrites temps

        float* hsbuf[2] = {hs0, hs1};
        float* h1buf[2] = {h1b0, h1b1};
        for (int t = 0; t < TT; ++t){
            const float* hsr = hsbuf[t & 1];
            float*       hsw = hsbuf[(t+1) & 1];
            const float* h1r = h1buf[(t+1) & 1];
            float*       h1w = h1buf[t & 1];
            kA<<<160, 512, 0, stream>>>(WhhP, embproj, lens, hsr, hsw, h1r, h1w,
                                        cs, c1, label, slot8, out, t);
            kB<<<160, 512, 0, stream>>>(WpredP, encprojT, bpred, h1w, joint, slot8, t);
            kC<<<256, 512, 0, stream>>>(WoutP, boutP, joint, slot8);
        }
        kFin<<<(BB*HH+255)/256, 256, 0, stream>>>(lens, slot8, hsbuf[0], h1buf[1], cs, c1, out);
        return;
    }

    // -------- fallback: basic per-step path (small ws) --------
    {
        size_t foff = 0;
        auto falloc = [&](size_t bytes) -> void* {
            void* p = ws + foff; foff += (bytes + 255) & ~(size_t)255; return p;
        };
        float* fhs0  = (float*)falloc(BH);
        float* fhs1  = (float*)falloc(BH);
        float* fh1b0 = (float*)falloc(BH);
        float* fh1b1 = (float*)falloc(BH);
        float* fcs   = (float*)falloc(BH);
        float* fc1   = (float*)falloc(BH);
        float* fjoint= (float*)falloc(BH);
        int* flabel  = (int*)falloc(BB*sizeof(int));
        unsigned long long* fslot = (unsigned long long*)falloc(BB*sizeof(unsigned long long));

        k_init<<<(BB*HH+255)/256, 256, 0, stream>>>(h0, c0, fhs0, fcs, flabel, fslot);
        float* hsbuf[2] = {fhs0, fhs1};
        float* h1buf[2] = {fh1b0, fh1b1};
        for (int t = 0; t < TT; ++t){
            const float* hsr = hsbuf[t & 1];
            float*       hsw = hsbuf[(t+1) & 1];
            const float* h1r = h1buf[(t+1) & 1];
            float*       h1w = h1buf[t & 1];
            k_p1o<<<160, 256, 0, stream>>>(Whh, Wih, emb, bih, bhh, lens,
                                           hsr, hsw, h1r, h1w, fcs, fc1, flabel, fslot, out, t);
            k_p2o<<<160, 128, 0, stream>>>(Wpred, Wenc, x, benc, bpred, h1w, fjoint, fslot, t);
            k_p3o<<<272, 256, 0, stream>>>(Wout, bout, fjoint, fslot);
        }
        k_finalo<<<(BB*HH+255)/256, 256, 0, stream>>>(lens, fslot, hsbuf[0], h1buf[1], fcs, fc1, out);
    }
}